// Round 1
// baseline (742.005 us; speedup 1.0000x reference)
//
#include <hip/hip_runtime.h>
#include <hip/hip_bf16.h>

// Problem constants
#define B_LON 15      // NLON
#define NW    32      // TYPE_OF_WINDOWS
#define NTOK  144     // N_TOK
#define DIM   192
#define NH    6
#define HD    32
#define K3    576     // 3*DIM
#define MROWS (B_LON*NW*NTOK)   // 69120
#define SCALE 0.17677669529663687f  // 32^-0.5

// ---------------------------------------------------------------------------
// Kernel 1: QKV GEMM.  out[m,d] = sum_k X[m,k]*W[d,k] + b[d]
// M=69120, N=576, K=192.  Tile 256x64, 256 threads, 8x8 microtile.
// Epilogue routes into q/k/v buffers laid out [bw, h, n, hd], q pre-scaled.
// ---------------------------------------------------------------------------
__global__ __launch_bounds__(256) void qkv_gemm_k(
    const float* __restrict__ X, const float* __restrict__ W,
    const float* __restrict__ Bv,
    float* __restrict__ qb, float* __restrict__ kb, float* __restrict__ vb) {
  __shared__ float As[8][256];
  __shared__ float Bs[8][64];
  const int t  = threadIdx.x;
  const int m0 = blockIdx.x * 256;
  const int n0 = blockIdx.y * 64;
  const int tx = t & 7;        // 8 cols of 8
  const int ty = t >> 3;       // 32 rows of 8
  const int ar0 = t >> 1;      // 0..127
  const int akc = (t & 1) * 4; // 0 or 4

  float acc[8][8];
#pragma unroll
  for (int r = 0; r < 8; ++r)
#pragma unroll
    for (int c = 0; c < 8; ++c) acc[r][c] = 0.f;

  for (int k0 = 0; k0 < 192; k0 += 8) {
    const float4 a0 = *(const float4*)(X + (size_t)(m0 + ar0) * 192 + k0 + akc);
    const float4 a1 = *(const float4*)(X + (size_t)(m0 + 128 + ar0) * 192 + k0 + akc);
    float4 b0;
    if (t < 128) b0 = *(const float4*)(W + (size_t)(n0 + ar0) * 192 + k0 + akc);
    __syncthreads();
    As[akc + 0][ar0] = a0.x; As[akc + 1][ar0] = a0.y;
    As[akc + 2][ar0] = a0.z; As[akc + 3][ar0] = a0.w;
    As[akc + 0][128 + ar0] = a1.x; As[akc + 1][128 + ar0] = a1.y;
    As[akc + 2][128 + ar0] = a1.z; As[akc + 3][128 + ar0] = a1.w;
    if (t < 128) {
      Bs[akc + 0][ar0] = b0.x; Bs[akc + 1][ar0] = b0.y;
      Bs[akc + 2][ar0] = b0.z; Bs[akc + 3][ar0] = b0.w;
    }
    __syncthreads();
#pragma unroll
    for (int kk = 0; kk < 8; ++kk) {
      const float4 av0 = *(const float4*)&As[kk][ty * 8];
      const float4 av1 = *(const float4*)&As[kk][ty * 8 + 4];
      const float4 bv0 = *(const float4*)&Bs[kk][tx * 8];
      const float4 bv1 = *(const float4*)&Bs[kk][tx * 8 + 4];
      const float a[8] = {av0.x, av0.y, av0.z, av0.w, av1.x, av1.y, av1.z, av1.w};
      const float b[8] = {bv0.x, bv0.y, bv0.z, bv0.w, bv1.x, bv1.y, bv1.z, bv1.w};
#pragma unroll
      for (int r = 0; r < 8; ++r)
#pragma unroll
        for (int c = 0; c < 8; ++c) acc[r][c] += a[r] * b[c];
    }
  }

  // Epilogue: d = n0 + tx*8 + c.  All 8 cols share s (qkv-slot) and h.
  const int colg = n0 + tx * 8;
  const int s    = colg / 192;
  const int rem  = colg % 192;
  const int h    = rem >> 5;
  const int dd   = rem & 31;       // multiple of 8
  float* dst = (s == 0) ? qb : (s == 1 ? kb : vb);
  const float sc = (s == 0) ? SCALE : 1.0f;
  float bias[8];
#pragma unroll
  for (int c = 0; c < 8; ++c) bias[c] = Bv[colg + c];

#pragma unroll
  for (int r = 0; r < 8; ++r) {
    const int m  = m0 + ty * 8 + r;
    const int bw = m / NTOK;
    const int n  = m % NTOK;
    float* p = dst + (((size_t)(bw * NH + h) * NTOK + n) * HD + dd);
    float4 o;
    o.x = (acc[r][0] + bias[0]) * sc; o.y = (acc[r][1] + bias[1]) * sc;
    o.z = (acc[r][2] + bias[2]) * sc; o.w = (acc[r][3] + bias[3]) * sc;
    *(float4*)p = o;
    o.x = (acc[r][4] + bias[4]) * sc; o.y = (acc[r][5] + bias[5]) * sc;
    o.z = (acc[r][6] + bias[6]) * sc; o.w = (acc[r][7] + bias[7]) * sc;
    *(float4*)(p + 4) = o;
  }
}

// ---------------------------------------------------------------------------
// Kernel 2: attention per (b,w,h).  2880 blocks x 256 threads.
// k,v staged in LDS (row stride 36 to avoid 16-way bank conflicts on
// stride-32 rows), S processed in 16-row groups.
// ---------------------------------------------------------------------------
__global__ __launch_bounds__(256) void attn_k(
    const float* __restrict__ qbuf, const float* __restrict__ kbuf,
    const float* __restrict__ vbuf, const float* __restrict__ mask,
    const float* __restrict__ btab, const int* __restrict__ pos,
    float* __restrict__ ao) {
  __shared__ float ks[NTOK * 36];
  __shared__ float vs[NTOK * 36];
  __shared__ float S[16 * NTOK];
  __shared__ float rinv[16];

  const int t   = threadIdx.x;
  const int idx = blockIdx.x;        // ((b*32+w)*6+h)
  const int bw  = idx / NH;
  const int h   = idx % NH;
  const int w   = bw & 31;
  const int wh  = w * NH + h;
  const size_t kvbase = (size_t)idx * (NTOK * HD);
  const float* maskp = mask + (size_t)bw * (NTOK * NTOK);

  // stage k, v into LDS (coalesced, float4)
  for (int i = t; i < NTOK * 8; i += 256) {   // 1152 float4s each
    const int j = i >> 3;
    const int c = (i & 7) * 4;
    *(float4*)&ks[j * 36 + c] = *(const float4*)(kbuf + kvbase + j * HD + c);
    *(float4*)&vs[j * 36 + c] = *(const float4*)(vbuf + kvbase + j * HD + c);
  }
  __syncthreads();

  const int ip  = t >> 5;          // 0..7 : row pair
  const int jq  = t & 31;          // S phase column lane
  const int sr  = t >> 4;          // softmax row 0..15
  const int ss  = t & 15;          // softmax lane
  const int jq2 = (t >> 3) & 3;    // O phase j quarter
  const int d0  = (t & 7) * 4;     // O phase d quad

  for (int g = 0; g < 9; ++g) {
    const int i0 = g * 16;
    const int i  = i0 + ip * 2;

    // --- S phase: rows i, i+1 ---
    float4 qa[8], qb4[8];
    const float* qp = qbuf + kvbase + (size_t)i * HD;
#pragma unroll
    for (int u = 0; u < 8; ++u) {
      qa[u]  = *(const float4*)(qp + u * 4);
      qb4[u] = *(const float4*)(qp + HD + u * 4);
    }
    const int njs = (jq < 16) ? 5 : 4;
    for (int jj = 0; jj < njs; ++jj) {
      const int j = jq + (jj << 5);
      float s0 = 0.f, s1 = 0.f;
#pragma unroll
      for (int u = 0; u < 8; ++u) {
        const float4 kv = *(const float4*)&ks[j * 36 + u * 4];
        s0 += qa[u].x * kv.x + qa[u].y * kv.y + qa[u].z * kv.z + qa[u].w * kv.w;
        s1 += qb4[u].x * kv.x + qb4[u].y * kv.y + qb4[u].z * kv.z + qb4[u].w * kv.w;
      }
      const int p0 = pos[i * NTOK + j];
      const int p1 = pos[(i + 1) * NTOK + j];
      const float b0 = btab[(size_t)p0 * (NW * NH) + wh];
      const float b1 = btab[(size_t)p1 * (NW * NH) + wh];
      const float m0 = maskp[i * NTOK + j];
      const float m1 = maskp[(i + 1) * NTOK + j];
      S[(ip * 2) * NTOK + j]     = s0 + b0 + m0;
      S[(ip * 2 + 1) * NTOK + j] = s1 + b1 + m1;
    }
    __syncthreads();

    // --- softmax: 16 rows x 16 lanes ---
    {
      float mx = -1e30f;
      for (int j = ss; j < NTOK; j += 16) mx = fmaxf(mx, S[sr * NTOK + j]);
#pragma unroll
      for (int off = 8; off >= 1; off >>= 1) mx = fmaxf(mx, __shfl_xor(mx, off));
      float sum = 0.f;
      for (int j = ss; j < NTOK; j += 16) {
        const float e = __expf(S[sr * NTOK + j] - mx);
        S[sr * NTOK + j] = e;
        sum += e;
      }
#pragma unroll
      for (int off = 8; off >= 1; off >>= 1) sum += __shfl_xor(sum, off);
      if (ss == 0) rinv[sr] = 1.0f / sum;
    }
    __syncthreads();

    // --- O phase: rows i,i+1 ; j quarter ; d quad ---
    float4 o0 = {0.f, 0.f, 0.f, 0.f}, o1 = {0.f, 0.f, 0.f, 0.f};
    const int jbase = jq2 * 36;
    for (int jj = 0; jj < 36; ++jj) {
      const int j = jbase + jj;
      const float p0 = S[(ip * 2) * NTOK + j];
      const float p1 = S[(ip * 2 + 1) * NTOK + j];
      const float4 v4 = *(const float4*)&vs[j * 36 + d0];
      o0.x += p0 * v4.x; o0.y += p0 * v4.y; o0.z += p0 * v4.z; o0.w += p0 * v4.w;
      o1.x += p1 * v4.x; o1.y += p1 * v4.y; o1.z += p1 * v4.z; o1.w += p1 * v4.w;
    }
#pragma unroll
    for (int off = 8; off <= 16; off <<= 1) {
      o0.x += __shfl_xor(o0.x, off); o0.y += __shfl_xor(o0.y, off);
      o0.z += __shfl_xor(o0.z, off); o0.w += __shfl_xor(o0.w, off);
      o1.x += __shfl_xor(o1.x, off); o1.y += __shfl_xor(o1.y, off);
      o1.z += __shfl_xor(o1.z, off); o1.w += __shfl_xor(o1.w, off);
    }
    if (jq2 == 0) {
      const float r0 = rinv[ip * 2];
      const float r1 = rinv[ip * 2 + 1];
      float* dst = ao + ((size_t)(bw * NTOK + i) * DIM + h * HD + d0);
      float4 w0 = {o0.x * r0, o0.y * r0, o0.z * r0, o0.w * r0};
      float4 w1 = {o1.x * r1, o1.y * r1, o1.z * r1, o1.w * r1};
      *(float4*)dst = w0;
      *(float4*)(dst + DIM) = w1;
    }
    __syncthreads();
  }
}

// ---------------------------------------------------------------------------
// Kernel 3: proj GEMM.  out[m,d] = sum_k AO[m,k]*W[d,k] + b[d]
// M=69120, N=192, K=192.  Same tiling as kernel 1.
// ---------------------------------------------------------------------------
__global__ __launch_bounds__(256) void proj_gemm_k(
    const float* __restrict__ AO, const float* __restrict__ W,
    const float* __restrict__ Bv, float* __restrict__ out) {
  __shared__ float As[8][256];
  __shared__ float Bs[8][64];
  const int t  = threadIdx.x;
  const int m0 = blockIdx.x * 256;
  const int n0 = blockIdx.y * 64;
  const int tx = t & 7;
  const int ty = t >> 3;
  const int ar0 = t >> 1;
  const int akc = (t & 1) * 4;

  float acc[8][8];
#pragma unroll
  for (int r = 0; r < 8; ++r)
#pragma unroll
    for (int c = 0; c < 8; ++c) acc[r][c] = 0.f;

  for (int k0 = 0; k0 < 192; k0 += 8) {
    const float4 a0 = *(const float4*)(AO + (size_t)(m0 + ar0) * 192 + k0 + akc);
    const float4 a1 = *(const float4*)(AO + (size_t)(m0 + 128 + ar0) * 192 + k0 + akc);
    float4 b0;
    if (t < 128) b0 = *(const float4*)(W + (size_t)(n0 + ar0) * 192 + k0 + akc);
    __syncthreads();
    As[akc + 0][ar0] = a0.x; As[akc + 1][ar0] = a0.y;
    As[akc + 2][ar0] = a0.z; As[akc + 3][ar0] = a0.w;
    As[akc + 0][128 + ar0] = a1.x; As[akc + 1][128 + ar0] = a1.y;
    As[akc + 2][128 + ar0] = a1.z; As[akc + 3][128 + ar0] = a1.w;
    if (t < 128) {
      Bs[akc + 0][ar0] = b0.x; Bs[akc + 1][ar0] = b0.y;
      Bs[akc + 2][ar0] = b0.z; Bs[akc + 3][ar0] = b0.w;
    }
    __syncthreads();
#pragma unroll
    for (int kk = 0; kk < 8; ++kk) {
      const float4 av0 = *(const float4*)&As[kk][ty * 8];
      const float4 av1 = *(const float4*)&As[kk][ty * 8 + 4];
      const float4 bv0 = *(const float4*)&Bs[kk][tx * 8];
      const float4 bv1 = *(const float4*)&Bs[kk][tx * 8 + 4];
      const float a[8] = {av0.x, av0.y, av0.z, av0.w, av1.x, av1.y, av1.z, av1.w};
      const float b[8] = {bv0.x, bv0.y, bv0.z, bv0.w, bv1.x, bv1.y, bv1.z, bv1.w};
#pragma unroll
      for (int r = 0; r < 8; ++r)
#pragma unroll
        for (int c = 0; c < 8; ++c) acc[r][c] += a[r] * b[c];
    }
  }

  const int colg = n0 + tx * 8;
  float bias[8];
#pragma unroll
  for (int c = 0; c < 8; ++c) bias[c] = Bv[colg + c];
#pragma unroll
  for (int r = 0; r < 8; ++r) {
    const int m = m0 + ty * 8 + r;
    float* p = out + (size_t)m * 192 + colg;
    float4 o;
    o.x = acc[r][0] + bias[0]; o.y = acc[r][1] + bias[1];
    o.z = acc[r][2] + bias[2]; o.w = acc[r][3] + bias[3];
    *(float4*)p = o;
    o.x = acc[r][4] + bias[4]; o.y = acc[r][5] + bias[5];
    o.z = acc[r][6] + bias[6]; o.w = acc[r][7] + bias[7];
    *(float4*)(p + 4) = o;
  }
}

// ---------------------------------------------------------------------------
extern "C" void kernel_launch(void* const* d_in, const int* in_sizes, int n_in,
                              void* d_out, int out_size, void* d_ws, size_t ws_size,
                              hipStream_t stream) {
  const float* x      = (const float*)d_in[0];
  const float* mask   = (const float*)d_in[1];
  const float* qkv_w  = (const float*)d_in[2];
  const float* qkv_b  = (const float*)d_in[3];
  const float* proj_w = (const float*)d_in[4];
  const float* proj_b = (const float*)d_in[5];
  const float* btab   = (const float*)d_in[6];
  const int*   pos    = (const int*)d_in[7];
  float* out = (float*)d_out;

  float* ws    = (float*)d_ws;
  const size_t sz = (size_t)MROWS * DIM;   // 13,271,040 floats
  float* qbuf  = ws;
  float* kbuf  = ws + sz;
  float* vbuf  = ws + 2 * sz;
  float* aobuf = ws + 3 * sz;

  qkv_gemm_k<<<dim3(MROWS / 256, K3 / 64), 256, 0, stream>>>(
      x, qkv_w, qkv_b, qbuf, kbuf, vbuf);
  attn_k<<<B_LON * NW * NH, 256, 0, stream>>>(
      qbuf, kbuf, vbuf, mask, btab, pos, aobuf);
  proj_gemm_k<<<dim3(MROWS / 256, DIM / 64), 256, 0, stream>>>(
      aobuf, proj_w, proj_b, out);
}

// Round 2
// 555.834 us; speedup vs baseline: 1.3349x; 1.3349x over previous
//
#include <hip/hip_runtime.h>
#include <hip/hip_bf16.h>

// Problem constants
#define B_LON 15      // NLON
#define NW    32      // TYPE_OF_WINDOWS
#define NTOK  144     // N_TOK
#define DIM   192
#define NH    6
#define HD    32
#define K3    576     // 3*DIM
#define MROWS (B_LON*NW*NTOK)   // 69120
#define SCALE 0.17677669529663687f  // 32^-0.5

typedef __attribute__((ext_vector_type(8))) short bf16x8;
typedef __attribute__((ext_vector_type(4))) float f32x4;

__device__ inline unsigned short f2bf(float f) {
  __bf16 h = (__bf16)f;
  return __builtin_bit_cast(unsigned short, h);
}

// ---------------------------------------------------------------------------
// MFMA GEMM template body (macro-free, two instantiations with different
// epilogues).  C[m,n] = sum_k A[m,k]*B[n,k]  (both row-major, K contiguous).
// Block tile 256x64, BK=32, 256 threads = 4 waves, each wave 64x64 via
// 4x4 grid of 16x16x32 bf16 MFMAs.  A,B staged fp32->bf16 into LDS.
// LDS row stride 40 (bf16) to break bank-conflict power-of-2 stride.
// ---------------------------------------------------------------------------

// Kernel 1: QKV GEMM. M=69120, N=576 (9 n-tiles), K=192 (6 k-steps).
// Epilogue routes into q/k/v buffers [bw, h, n, hd], q pre-scaled.
__global__ __launch_bounds__(256) void qkv_gemm_k(
    const float* __restrict__ X, const float* __restrict__ W,
    const float* __restrict__ Bv,
    float* __restrict__ qb, float* __restrict__ kb, float* __restrict__ vb) {
  __shared__ unsigned short As[256 * 40];
  __shared__ unsigned short Bs[64 * 40];
  const int t    = threadIdx.x;
  const int n0   = blockIdx.x * 64;
  const int m0   = blockIdx.y * 256;
  const int w    = t >> 6;        // wave 0..3
  const int lane = t & 63;
  const int ln15 = lane & 15;
  const int quad = lane >> 4;
  const int sr   = t >> 3;        // staging row 0..31
  const int sc   = (t & 7) * 4;   // staging col 0,4,..,28

  f32x4 acc[4][4];
#pragma unroll
  for (int i = 0; i < 4; ++i)
#pragma unroll
    for (int j = 0; j < 4; ++j) acc[i][j] = (f32x4){0.f, 0.f, 0.f, 0.f};

  for (int k0 = 0; k0 < 192; k0 += 32) {
    float4 av[8], bv2[2];
#pragma unroll
    for (int it = 0; it < 8; ++it)
      av[it] = *(const float4*)(X + (size_t)(m0 + it * 32 + sr) * 192 + k0 + sc);
#pragma unroll
    for (int it = 0; it < 2; ++it)
      bv2[it] = *(const float4*)(W + (size_t)(n0 + it * 32 + sr) * 192 + k0 + sc);
    __syncthreads();
#pragma unroll
    for (int it = 0; it < 8; ++it) {
      ushort4 u = {f2bf(av[it].x), f2bf(av[it].y), f2bf(av[it].z), f2bf(av[it].w)};
      *(ushort4*)&As[(it * 32 + sr) * 40 + sc] = u;
    }
#pragma unroll
    for (int it = 0; it < 2; ++it) {
      ushort4 u = {f2bf(bv2[it].x), f2bf(bv2[it].y), f2bf(bv2[it].z), f2bf(bv2[it].w)};
      *(ushort4*)&Bs[(it * 32 + sr) * 40 + sc] = u;
    }
    __syncthreads();

    bf16x8 af[4], bfr[4];
#pragma unroll
    for (int mt = 0; mt < 4; ++mt)
      af[mt] = *(bf16x8*)&As[(w * 64 + mt * 16 + ln15) * 40 + quad * 8];
#pragma unroll
    for (int nt = 0; nt < 4; ++nt)
      bfr[nt] = *(bf16x8*)&Bs[(nt * 16 + ln15) * 40 + quad * 8];
#pragma unroll
    for (int mt = 0; mt < 4; ++mt)
#pragma unroll
      for (int nt = 0; nt < 4; ++nt)
        acc[mt][nt] = __builtin_amdgcn_mfma_f32_16x16x32_bf16(
            af[mt], bfr[nt], acc[mt][nt], 0, 0, 0);
    __syncthreads();
  }

  // Epilogue.  D layout: col = lane&15 (n), row = quad*4 + r (m).
#pragma unroll
  for (int nt = 0; nt < 4; ++nt) {
    const int colg = n0 + nt * 16 + ln15;
    const int s    = colg / 192;
    const int rem  = colg % 192;
    const int h    = rem >> 5;
    const int dd   = rem & 31;
    float* dst = (s == 0) ? qb : (s == 1 ? kb : vb);
    const float sc2 = (s == 0) ? SCALE : 1.0f;
    const float bias = Bv[colg];
#pragma unroll
    for (int mt = 0; mt < 4; ++mt) {
#pragma unroll
      for (int r = 0; r < 4; ++r) {
        const int m  = m0 + w * 64 + mt * 16 + quad * 4 + r;
        const int bw = m / NTOK;
        const int n  = m % NTOK;
        dst[(((size_t)(bw * NH + h) * NTOK + n) * HD + dd)] =
            (acc[mt][nt][r] + bias) * sc2;
      }
    }
  }
}

// Kernel 3: proj GEMM. M=69120, N=192 (3 n-tiles), K=192.
__global__ __launch_bounds__(256) void proj_gemm_k(
    const float* __restrict__ AO, const float* __restrict__ W,
    const float* __restrict__ Bv, float* __restrict__ out) {
  __shared__ unsigned short As[256 * 40];
  __shared__ unsigned short Bs[64 * 40];
  const int t    = threadIdx.x;
  const int n0   = blockIdx.x * 64;
  const int m0   = blockIdx.y * 256;
  const int w    = t >> 6;
  const int lane = t & 63;
  const int ln15 = lane & 15;
  const int quad = lane >> 4;
  const int sr   = t >> 3;
  const int sc   = (t & 7) * 4;

  f32x4 acc[4][4];
#pragma unroll
  for (int i = 0; i < 4; ++i)
#pragma unroll
    for (int j = 0; j < 4; ++j) acc[i][j] = (f32x4){0.f, 0.f, 0.f, 0.f};

  for (int k0 = 0; k0 < 192; k0 += 32) {
    float4 av[8], bv2[2];
#pragma unroll
    for (int it = 0; it < 8; ++it)
      av[it] = *(const float4*)(AO + (size_t)(m0 + it * 32 + sr) * 192 + k0 + sc);
#pragma unroll
    for (int it = 0; it < 2; ++it)
      bv2[it] = *(const float4*)(W + (size_t)(n0 + it * 32 + sr) * 192 + k0 + sc);
    __syncthreads();
#pragma unroll
    for (int it = 0; it < 8; ++it) {
      ushort4 u = {f2bf(av[it].x), f2bf(av[it].y), f2bf(av[it].z), f2bf(av[it].w)};
      *(ushort4*)&As[(it * 32 + sr) * 40 + sc] = u;
    }
#pragma unroll
    for (int it = 0; it < 2; ++it) {
      ushort4 u = {f2bf(bv2[it].x), f2bf(bv2[it].y), f2bf(bv2[it].z), f2bf(bv2[it].w)};
      *(ushort4*)&Bs[(it * 32 + sr) * 40 + sc] = u;
    }
    __syncthreads();

    bf16x8 af[4], bfr[4];
#pragma unroll
    for (int mt = 0; mt < 4; ++mt)
      af[mt] = *(bf16x8*)&As[(w * 64 + mt * 16 + ln15) * 40 + quad * 8];
#pragma unroll
    for (int nt = 0; nt < 4; ++nt)
      bfr[nt] = *(bf16x8*)&Bs[(nt * 16 + ln15) * 40 + quad * 8];
#pragma unroll
    for (int mt = 0; mt < 4; ++mt)
#pragma unroll
      for (int nt = 0; nt < 4; ++nt)
        acc[mt][nt] = __builtin_amdgcn_mfma_f32_16x16x32_bf16(
            af[mt], bfr[nt], acc[mt][nt], 0, 0, 0);
    __syncthreads();
  }

#pragma unroll
  for (int nt = 0; nt < 4; ++nt) {
    const int colg = n0 + nt * 16 + ln15;
    const float bias = Bv[colg];
#pragma unroll
    for (int mt = 0; mt < 4; ++mt) {
#pragma unroll
      for (int r = 0; r < 4; ++r) {
        const int m = m0 + w * 64 + mt * 16 + quad * 4 + r;
        out[(size_t)m * 192 + colg] = acc[mt][nt][r] + bias;
      }
    }
  }
}

// ---------------------------------------------------------------------------
// Kernel 2: attention per (b,w,h).  UNCHANGED from round 1.
// ---------------------------------------------------------------------------
__global__ __launch_bounds__(256) void attn_k(
    const float* __restrict__ qbuf, const float* __restrict__ kbuf,
    const float* __restrict__ vbuf, const float* __restrict__ mask,
    const float* __restrict__ btab, const int* __restrict__ pos,
    float* __restrict__ ao) {
  __shared__ float ks[NTOK * 36];
  __shared__ float vs[NTOK * 36];
  __shared__ float S[16 * NTOK];
  __shared__ float rinv[16];

  const int t   = threadIdx.x;
  const int idx = blockIdx.x;        // ((b*32+w)*6+h)
  const int bw  = idx / NH;
  const int h   = idx % NH;
  const int w   = bw & 31;
  const int wh  = w * NH + h;
  const size_t kvbase = (size_t)idx * (NTOK * HD);
  const float* maskp = mask + (size_t)bw * (NTOK * NTOK);

  for (int i = t; i < NTOK * 8; i += 256) {
    const int j = i >> 3;
    const int c = (i & 7) * 4;
    *(float4*)&ks[j * 36 + c] = *(const float4*)(kbuf + kvbase + j * HD + c);
    *(float4*)&vs[j * 36 + c] = *(const float4*)(vbuf + kvbase + j * HD + c);
  }
  __syncthreads();

  const int ip  = t >> 5;
  const int jq  = t & 31;
  const int sr  = t >> 4;
  const int ss  = t & 15;
  const int jq2 = (t >> 3) & 3;
  const int d0  = (t & 7) * 4;

  for (int g = 0; g < 9; ++g) {
    const int i0 = g * 16;
    const int i  = i0 + ip * 2;

    float4 qa[8], qb4[8];
    const float* qp = qbuf + kvbase + (size_t)i * HD;
#pragma unroll
    for (int u = 0; u < 8; ++u) {
      qa[u]  = *(const float4*)(qp + u * 4);
      qb4[u] = *(const float4*)(qp + HD + u * 4);
    }
    const int njs = (jq < 16) ? 5 : 4;
    for (int jj = 0; jj < njs; ++jj) {
      const int j = jq + (jj << 5);
      float s0 = 0.f, s1 = 0.f;
#pragma unroll
      for (int u = 0; u < 8; ++u) {
        const float4 kv = *(const float4*)&ks[j * 36 + u * 4];
        s0 += qa[u].x * kv.x + qa[u].y * kv.y + qa[u].z * kv.z + qa[u].w * kv.w;
        s1 += qb4[u].x * kv.x + qb4[u].y * kv.y + qb4[u].z * kv.z + qb4[u].w * kv.w;
      }
      const int p0 = pos[i * NTOK + j];
      const int p1 = pos[(i + 1) * NTOK + j];
      const float b0 = btab[(size_t)p0 * (NW * NH) + wh];
      const float b1 = btab[(size_t)p1 * (NW * NH) + wh];
      const float m0 = maskp[i * NTOK + j];
      const float m1 = maskp[(i + 1) * NTOK + j];
      S[(ip * 2) * NTOK + j]     = s0 + b0 + m0;
      S[(ip * 2 + 1) * NTOK + j] = s1 + b1 + m1;
    }
    __syncthreads();

    {
      float mx = -1e30f;
      for (int j = ss; j < NTOK; j += 16) mx = fmaxf(mx, S[sr * NTOK + j]);
#pragma unroll
      for (int off = 8; off >= 1; off >>= 1) mx = fmaxf(mx, __shfl_xor(mx, off));
      float sum = 0.f;
      for (int j = ss; j < NTOK; j += 16) {
        const float e = __expf(S[sr * NTOK + j] - mx);
        S[sr * NTOK + j] = e;
        sum += e;
      }
#pragma unroll
      for (int off = 8; off >= 1; off >>= 1) sum += __shfl_xor(sum, off);
      if (ss == 0) rinv[sr] = 1.0f / sum;
    }
    __syncthreads();

    float4 o0 = {0.f, 0.f, 0.f, 0.f}, o1 = {0.f, 0.f, 0.f, 0.f};
    const int jbase = jq2 * 36;
    for (int jj = 0; jj < 36; ++jj) {
      const int j = jbase + jj;
      const float p0 = S[(ip * 2) * NTOK + j];
      const float p1 = S[(ip * 2 + 1) * NTOK + j];
      const float4 v4 = *(const float4*)&vs[j * 36 + d0];
      o0.x += p0 * v4.x; o0.y += p0 * v4.y; o0.z += p0 * v4.z; o0.w += p0 * v4.w;
      o1.x += p1 * v4.x; o1.y += p1 * v4.y; o1.z += p1 * v4.z; o1.w += p1 * v4.w;
    }
#pragma unroll
    for (int off = 8; off <= 16; off <<= 1) {
      o0.x += __shfl_xor(o0.x, off); o0.y += __shfl_xor(o0.y, off);
      o0.z += __shfl_xor(o0.z, off); o0.w += __shfl_xor(o0.w, off);
      o1.x += __shfl_xor(o1.x, off); o1.y += __shfl_xor(o1.y, off);
      o1.z += __shfl_xor(o1.z, off); o1.w += __shfl_xor(o1.w, off);
    }
    if (jq2 == 0) {
      const float r0 = rinv[ip * 2];
      const float r1 = rinv[ip * 2 + 1];
      float* dst = ao + ((size_t)(bw * NTOK + i) * DIM + h * HD + d0);
      float4 w0 = {o0.x * r0, o0.y * r0, o0.z * r0, o0.w * r0};
      float4 w1 = {o1.x * r1, o1.y * r1, o1.z * r1, o1.w * r1};
      *(float4*)dst = w0;
      *(float4*)(dst + DIM) = w1;
    }
    __syncthreads();
  }
}

// ---------------------------------------------------------------------------
extern "C" void kernel_launch(void* const* d_in, const int* in_sizes, int n_in,
                              void* d_out, int out_size, void* d_ws, size_t ws_size,
                              hipStream_t stream) {
  const float* x      = (const float*)d_in[0];
  const float* mask   = (const float*)d_in[1];
  const float* qkv_w  = (const float*)d_in[2];
  const float* qkv_b  = (const float*)d_in[3];
  const float* proj_w = (const float*)d_in[4];
  const float* proj_b = (const float*)d_in[5];
  const float* btab   = (const float*)d_in[6];
  const int*   pos    = (const int*)d_in[7];
  float* out = (float*)d_out;

  float* ws    = (float*)d_ws;
  const size_t sz = (size_t)MROWS * DIM;   // 13,271,040 floats
  float* qbuf  = ws;
  float* kbuf  = ws + sz;
  float* vbuf  = ws + 2 * sz;
  float* aobuf = ws + 3 * sz;

  // grid.x = n-tiles so consecutive blocks share the A-tile (L2 reuse)
  qkv_gemm_k<<<dim3(K3 / 64, MROWS / 256), 256, 0, stream>>>(
      x, qkv_w, qkv_b, qbuf, kbuf, vbuf);
  attn_k<<<B_LON * NW * NH, 256, 0, stream>>>(
      qbuf, kbuf, vbuf, mask, btab, pos, aobuf);
  proj_gemm_k<<<dim3(DIM / 64, MROWS / 256), 256, 0, stream>>>(
      aobuf, proj_w, proj_b, out);
}

// Round 3
// 426.243 us; speedup vs baseline: 1.7408x; 1.3040x over previous
//
#include <hip/hip_runtime.h>
#include <hip/hip_bf16.h>

// Problem constants
#define B_LON 15      // NLON
#define NW    32      // TYPE_OF_WINDOWS
#define NTOK  144     // N_TOK
#define DIM   192
#define NH    6
#define HD    32
#define K3    576     // 3*DIM
#define MROWS (B_LON*NW*NTOK)   // 69120
#define SCALE 0.17677669529663687f  // 32^-0.5

typedef __attribute__((ext_vector_type(8))) short bf16x8;
typedef __attribute__((ext_vector_type(8))) unsigned short u16x8;
typedef __attribute__((ext_vector_type(4))) float f32x4;

__device__ inline unsigned short f2bf(float f) {
  __bf16 h = (__bf16)f;
  return __builtin_bit_cast(unsigned short, h);
}

// ---------------------------------------------------------------------------
// Kernel 1: QKV GEMM. M=69120, N=576, K=192. fp32 in, bf16 out.
// Epilogue: q (scaled) and k in [bw,h,n,d]; v TRANSPOSED to [bw,h,d,n].
// ---------------------------------------------------------------------------
__global__ __launch_bounds__(256) void qkv_gemm_k(
    const float* __restrict__ X, const float* __restrict__ W,
    const float* __restrict__ Bv,
    unsigned short* __restrict__ qb, unsigned short* __restrict__ kb,
    unsigned short* __restrict__ vb) {
  __shared__ unsigned short As[256 * 40];
  __shared__ unsigned short Bs[64 * 40];
  const int t    = threadIdx.x;
  const int n0   = blockIdx.x * 64;
  const int m0   = blockIdx.y * 256;
  const int w    = t >> 6;
  const int lane = t & 63;
  const int ln15 = lane & 15;
  const int quad = lane >> 4;
  const int sr   = t >> 3;
  const int sc   = (t & 7) * 4;

  f32x4 acc[4][4];
#pragma unroll
  for (int i = 0; i < 4; ++i)
#pragma unroll
    for (int j = 0; j < 4; ++j) acc[i][j] = (f32x4){0.f, 0.f, 0.f, 0.f};

  for (int k0 = 0; k0 < 192; k0 += 32) {
    float4 av[8], bv2[2];
#pragma unroll
    for (int it = 0; it < 8; ++it)
      av[it] = *(const float4*)(X + (size_t)(m0 + it * 32 + sr) * 192 + k0 + sc);
#pragma unroll
    for (int it = 0; it < 2; ++it)
      bv2[it] = *(const float4*)(W + (size_t)(n0 + it * 32 + sr) * 192 + k0 + sc);
    __syncthreads();
#pragma unroll
    for (int it = 0; it < 8; ++it) {
      ushort4 u = {f2bf(av[it].x), f2bf(av[it].y), f2bf(av[it].z), f2bf(av[it].w)};
      *(ushort4*)&As[(it * 32 + sr) * 40 + sc] = u;
    }
#pragma unroll
    for (int it = 0; it < 2; ++it) {
      ushort4 u = {f2bf(bv2[it].x), f2bf(bv2[it].y), f2bf(bv2[it].z), f2bf(bv2[it].w)};
      *(ushort4*)&Bs[(it * 32 + sr) * 40 + sc] = u;
    }
    __syncthreads();

    bf16x8 af[4], bfr[4];
#pragma unroll
    for (int mt = 0; mt < 4; ++mt)
      af[mt] = *(bf16x8*)&As[(w * 64 + mt * 16 + ln15) * 40 + quad * 8];
#pragma unroll
    for (int nt = 0; nt < 4; ++nt)
      bfr[nt] = *(bf16x8*)&Bs[(nt * 16 + ln15) * 40 + quad * 8];
#pragma unroll
    for (int mt = 0; mt < 4; ++mt)
#pragma unroll
      for (int nt = 0; nt < 4; ++nt)
        acc[mt][nt] = __builtin_amdgcn_mfma_f32_16x16x32_bf16(
            af[mt], bfr[nt], acc[mt][nt], 0, 0, 0);
    __syncthreads();
  }

  // Epilogue.  D layout: col = ln15 (n), row = quad*4 + r (m).
#pragma unroll
  for (int nt = 0; nt < 4; ++nt) {
    const int colg = n0 + nt * 16 + ln15;
    const int s    = colg / 192;
    const int rem  = colg % 192;
    const int h    = rem >> 5;
    const int dd   = rem & 31;
    const float bias = Bv[colg];
    const float sc2  = (s == 0) ? SCALE : 1.0f;
    unsigned short* dst = (s == 0) ? qb : (s == 1 ? kb : vb);
#pragma unroll
    for (int mt = 0; mt < 4; ++mt) {
#pragma unroll
      for (int r = 0; r < 4; ++r) {
        const int m  = m0 + w * 64 + mt * 16 + quad * 4 + r;
        const int bw = m / NTOK;
        const int n  = m % NTOK;
        const unsigned short val = f2bf((acc[mt][nt][r] + bias) * sc2);
        if (s < 2)
          dst[((size_t)(bw * NH + h) * NTOK + n) * HD + dd] = val;       // [bw,h,n,d]
        else
          dst[((size_t)(bw * NH + h) * HD + dd) * NTOK + n] = val;       // [bw,h,d,n]
      }
    }
  }
}

// ---------------------------------------------------------------------------
// Kernel 2: MFMA attention.  Grid = 480*(NH/2) = 1440 blocks; 128 threads =
// 2 waves, wave handles head h = (blockIdx%3)*2 + wave.  No __syncthreads.
// K and V^T fragments preloaded once into registers (group-invariant).
// Only LDS use: per-wave P round-trip (C-layout -> A-layout), stride 168.
// ---------------------------------------------------------------------------
__global__ __launch_bounds__(128) void attn_k(
    const unsigned short* __restrict__ qbuf, const unsigned short* __restrict__ kbuf,
    const unsigned short* __restrict__ vbuf, const float* __restrict__ mask,
    const float* __restrict__ btab, const int* __restrict__ pos,
    unsigned short* __restrict__ ao) {
  __shared__ unsigned short Ps[2 * 16 * 168];

  const int t    = threadIdx.x;
  const int wave = t >> 6;
  const int lane = t & 63;
  const int ln15 = lane & 15;
  const int quad = lane >> 4;
  const int bw   = blockIdx.x / 3;
  const int hp   = blockIdx.x % 3;
  const int h    = hp * 2 + wave;
  const int w    = bw & 31;
  const int wh   = w * NH + h;
  const size_t hb = (size_t)(bw * NH + h) * (NTOK * HD);
  const unsigned short* qh = qbuf + hb;
  const unsigned short* kh = kbuf + hb;
  const unsigned short* vh = vbuf + hb;           // [32][144] (transposed)
  const float* maskp = mask + (size_t)bw * (NTOK * NTOK);
  unsigned short* ps = &Ps[wave * 16 * 168];

  // zero the K-pad columns 144..159 of P (once; stores below never touch them)
  {
    ushort4 z = {0, 0, 0, 0};
    *(ushort4*)&ps[(lane >> 2) * 168 + 144 + (lane & 3) * 4] = z;
  }

  // Preload K fragments (B operand, n=token j, k=d) — group-invariant.
  bf16x8 kf[9];
#pragma unroll
  for (int jt = 0; jt < 9; ++jt)
    kf[jt] = *(const bf16x8*)&kh[(jt * 16 + ln15) * HD + quad * 8];

  // Preload V^T fragments (B operand, n=d, k=token j). kt=4 tail reads past
  // 144 — multiplied by zeroed P columns, so harmless (ws has slack).
  bf16x8 vf[5][2];
#pragma unroll
  for (int kt = 0; kt < 5; ++kt)
#pragma unroll
    for (int nt = 0; nt < 2; ++nt)
      vf[kt][nt] = *(const bf16x8*)&vh[(nt * 16 + ln15) * NTOK + kt * 32 + quad * 8];

  for (int g = 0; g < 9; ++g) {
    const int i0 = g * 16;
    const int ib = i0 + quad * 4;

    // S = Q K^T  (A-frag from global; 9 n-tiles)
    const bf16x8 qf = *(const bf16x8*)&qh[(i0 + ln15) * HD + quad * 8];
    f32x4 s[9];
#pragma unroll
    for (int jt = 0; jt < 9; ++jt) s[jt] = (f32x4){0.f, 0.f, 0.f, 0.f};
#pragma unroll
    for (int jt = 0; jt < 9; ++jt)
      s[jt] = __builtin_amdgcn_mfma_f32_16x16x32_bf16(qf, kf[jt], s[jt], 0, 0, 0);

    // + bias (gathered) + mask
#pragma unroll
    for (int jt = 0; jt < 9; ++jt) {
      const int j = jt * 16 + ln15;
#pragma unroll
      for (int r = 0; r < 4; ++r) {
        const int ij = (ib + r) * NTOK + j;
        s[jt][r] += btab[(size_t)pos[ij] * (NW * NH) + wh] + maskp[ij];
      }
    }

    // softmax over j (row = ib+r lives in the 16-lane ln15 group)
    float rinv[4];
#pragma unroll
    for (int r = 0; r < 4; ++r) {
      float mx = s[0][r];
#pragma unroll
      for (int jt = 1; jt < 9; ++jt) mx = fmaxf(mx, s[jt][r]);
#pragma unroll
      for (int off = 1; off < 16; off <<= 1) mx = fmaxf(mx, __shfl_xor(mx, off));
      float sum = 0.f;
#pragma unroll
      for (int jt = 0; jt < 9; ++jt) {
        const float e = __expf(s[jt][r] - mx);
        s[jt][r] = e;
        sum += e;
      }
#pragma unroll
      for (int off = 1; off < 16; off <<= 1) sum += __shfl_xor(sum, off);
      rinv[r] = 1.0f / sum;
    }

    // P: C-layout -> LDS -> A-layout (wave-internal, in-order DS pipe)
#pragma unroll
    for (int jt = 0; jt < 9; ++jt)
#pragma unroll
      for (int r = 0; r < 4; ++r)
        ps[(quad * 4 + r) * 168 + jt * 16 + ln15] = f2bf(s[jt][r]);

    // O = P V   (K padded to 160)
    f32x4 o[2] = {{0.f, 0.f, 0.f, 0.f}, {0.f, 0.f, 0.f, 0.f}};
#pragma unroll
    for (int kt = 0; kt < 5; ++kt) {
      const bf16x8 pf = *(const bf16x8*)&ps[ln15 * 168 + kt * 32 + quad * 8];
#pragma unroll
      for (int nt = 0; nt < 2; ++nt)
        o[nt] = __builtin_amdgcn_mfma_f32_16x16x32_bf16(pf, vf[kt][nt], o[nt], 0, 0, 0);
    }

    // store O (bf16) into [m=bw*144+i][c=h*32+d]
#pragma unroll
    for (int nt = 0; nt < 2; ++nt)
#pragma unroll
      for (int r = 0; r < 4; ++r)
        ao[(size_t)(bw * NTOK + ib + r) * DIM + h * HD + nt * 16 + ln15] =
            f2bf(o[nt][r] * rinv[r]);
  }
}

// ---------------------------------------------------------------------------
// Kernel 3: proj GEMM. A = bf16 attention output, B = fp32 weights.
// ---------------------------------------------------------------------------
__global__ __launch_bounds__(256) void proj_gemm_k(
    const unsigned short* __restrict__ AO, const float* __restrict__ W,
    const float* __restrict__ Bv, float* __restrict__ out) {
  __shared__ unsigned short As[256 * 40];
  __shared__ unsigned short Bs[64 * 40];
  const int t    = threadIdx.x;
  const int n0   = blockIdx.x * 64;
  const int m0   = blockIdx.y * 256;
  const int w    = t >> 6;
  const int lane = t & 63;
  const int ln15 = lane & 15;
  const int quad = lane >> 4;
  const int sr   = t >> 3;
  const int sc   = (t & 7) * 4;
  const int arow = t >> 2;        // 0..63
  const int acol = (t & 3) * 8;   // 0,8,16,24

  f32x4 acc[4][4];
#pragma unroll
  for (int i = 0; i < 4; ++i)
#pragma unroll
    for (int j = 0; j < 4; ++j) acc[i][j] = (f32x4){0.f, 0.f, 0.f, 0.f};

  for (int k0 = 0; k0 < 192; k0 += 32) {
    u16x8 av[4];
#pragma unroll
    for (int it = 0; it < 4; ++it)
      av[it] = *(const u16x8*)(AO + (size_t)(m0 + it * 64 + arow) * 192 + k0 + acol);
    float4 bv2[2];
#pragma unroll
    for (int it = 0; it < 2; ++it)
      bv2[it] = *(const float4*)(W + (size_t)(n0 + it * 32 + sr) * 192 + k0 + sc);
    __syncthreads();
#pragma unroll
    for (int it = 0; it < 4; ++it)
      *(u16x8*)&As[(it * 64 + arow) * 40 + acol] = av[it];
#pragma unroll
    for (int it = 0; it < 2; ++it) {
      ushort4 u = {f2bf(bv2[it].x), f2bf(bv2[it].y), f2bf(bv2[it].z), f2bf(bv2[it].w)};
      *(ushort4*)&Bs[(it * 32 + sr) * 40 + sc] = u;
    }
    __syncthreads();

    bf16x8 af[4], bfr[4];
#pragma unroll
    for (int mt = 0; mt < 4; ++mt)
      af[mt] = *(bf16x8*)&As[(w * 64 + mt * 16 + ln15) * 40 + quad * 8];
#pragma unroll
    for (int nt = 0; nt < 4; ++nt)
      bfr[nt] = *(bf16x8*)&Bs[(nt * 16 + ln15) * 40 + quad * 8];
#pragma unroll
    for (int mt = 0; mt < 4; ++mt)
#pragma unroll
      for (int nt = 0; nt < 4; ++nt)
        acc[mt][nt] = __builtin_amdgcn_mfma_f32_16x16x32_bf16(
            af[mt], bfr[nt], acc[mt][nt], 0, 0, 0);
    __syncthreads();
  }

#pragma unroll
  for (int nt = 0; nt < 4; ++nt) {
    const int colg = n0 + nt * 16 + ln15;
    const float bias = Bv[colg];
#pragma unroll
    for (int mt = 0; mt < 4; ++mt) {
#pragma unroll
      for (int r = 0; r < 4; ++r) {
        const int m = m0 + w * 64 + mt * 16 + quad * 4 + r;
        out[(size_t)m * 192 + colg] = acc[mt][nt][r] + bias;
      }
    }
  }
}

// ---------------------------------------------------------------------------
extern "C" void kernel_launch(void* const* d_in, const int* in_sizes, int n_in,
                              void* d_out, int out_size, void* d_ws, size_t ws_size,
                              hipStream_t stream) {
  const float* x      = (const float*)d_in[0];
  const float* mask   = (const float*)d_in[1];
  const float* qkv_w  = (const float*)d_in[2];
  const float* qkv_b  = (const float*)d_in[3];
  const float* proj_w = (const float*)d_in[4];
  const float* proj_b = (const float*)d_in[5];
  const float* btab   = (const float*)d_in[6];
  const int*   pos    = (const int*)d_in[7];
  float* out = (float*)d_out;

  unsigned short* ws = (unsigned short*)d_ws;
  const size_t sz = (size_t)MROWS * DIM;   // 13,271,040 elements
  unsigned short* qbuf  = ws;
  unsigned short* kbuf  = ws + sz;
  unsigned short* vbuf  = ws + 2 * sz;
  unsigned short* aobuf = ws + 3 * sz + 256;   // 256-short slack for V^T tail reads

  qkv_gemm_k<<<dim3(K3 / 64, MROWS / 256), 256, 0, stream>>>(
      x, qkv_w, qkv_b, qbuf, kbuf, vbuf);
  attn_k<<<B_LON * NW * (NH / 2), 128, 0, stream>>>(
      qbuf, kbuf, vbuf, mask, btab, pos, aobuf);
  proj_gemm_k<<<dim3(DIM / 64, MROWS / 256), 256, 0, stream>>>(
      aobuf, proj_w, proj_b, out);
}

// Round 4
// 406.304 us; speedup vs baseline: 1.8262x; 1.0491x over previous
//
#include <hip/hip_runtime.h>
#include <hip/hip_bf16.h>

// Problem constants
#define B_LON 15      // NLON
#define NW    32      // TYPE_OF_WINDOWS
#define NTOK  144     // N_TOK
#define DIM   192
#define NH    6
#define HD    32
#define K3    576     // 3*DIM
#define MROWS (B_LON*NW*NTOK)   // 69120
#define NN    (NTOK*NTOK)       // 20736
#define SCALE 0.17677669529663687f  // 32^-0.5

typedef __attribute__((ext_vector_type(8))) short bf16x8;
typedef __attribute__((ext_vector_type(8))) unsigned short u16x8;
typedef __attribute__((ext_vector_type(4))) float f32x4;

__device__ inline unsigned short f2bf(float f) {
  __bf16 h = (__bf16)f;
  return __builtin_bit_cast(unsigned short, h);
}
__device__ inline float bf2f(unsigned short u) {
  union { unsigned int i; float f; } c;
  c.i = ((unsigned int)u) << 16;
  return c.f;
}

// ---------------------------------------------------------------------------
// Kernel 0: bias precompute.  biasb[wh][ij] = bf16(btab[pos[ij]*192 + wh]).
// Turns 60M dependent in-attention gathers into 4M independent ones.
// ---------------------------------------------------------------------------
__global__ __launch_bounds__(256) void bias_pre_k(
    const float* __restrict__ btab, const int* __restrict__ pos,
    unsigned short* __restrict__ biasb) {
  const int wh  = blockIdx.x;          // 0..191
  const int seg = blockIdx.y * 2304;   // 9 segs of 2304
  unsigned short* dst = biasb + (size_t)wh * NN;
#pragma unroll
  for (int it = 0; it < 9; ++it) {
    const int e = seg + it * 256 + threadIdx.x;
    dst[e] = f2bf(btab[(size_t)pos[e] * (NW * NH) + wh]);
  }
}

// ---------------------------------------------------------------------------
// Kernel 1: QKV GEMM. M=69120, N=576, K=192. fp32 in, bf16 out.
// Epilogue: q (scaled) and k in [bw,h,n,d]; v TRANSPOSED to [bw,h,d,n].
// ---------------------------------------------------------------------------
__global__ __launch_bounds__(256) void qkv_gemm_k(
    const float* __restrict__ X, const float* __restrict__ W,
    const float* __restrict__ Bv,
    unsigned short* __restrict__ qb, unsigned short* __restrict__ kb,
    unsigned short* __restrict__ vb) {
  __shared__ unsigned short As[256 * 40];
  __shared__ unsigned short Bs[64 * 40];
  const int t    = threadIdx.x;
  const int n0   = blockIdx.x * 64;
  const int m0   = blockIdx.y * 256;
  const int w    = t >> 6;
  const int lane = t & 63;
  const int ln15 = lane & 15;
  const int quad = lane >> 4;
  const int sr   = t >> 3;
  const int sc   = (t & 7) * 4;

  f32x4 acc[4][4];
#pragma unroll
  for (int i = 0; i < 4; ++i)
#pragma unroll
    for (int j = 0; j < 4; ++j) acc[i][j] = (f32x4){0.f, 0.f, 0.f, 0.f};

  for (int k0 = 0; k0 < 192; k0 += 32) {
    float4 av[8], bv2[2];
#pragma unroll
    for (int it = 0; it < 8; ++it)
      av[it] = *(const float4*)(X + (size_t)(m0 + it * 32 + sr) * 192 + k0 + sc);
#pragma unroll
    for (int it = 0; it < 2; ++it)
      bv2[it] = *(const float4*)(W + (size_t)(n0 + it * 32 + sr) * 192 + k0 + sc);
    __syncthreads();
#pragma unroll
    for (int it = 0; it < 8; ++it) {
      ushort4 u = {f2bf(av[it].x), f2bf(av[it].y), f2bf(av[it].z), f2bf(av[it].w)};
      *(ushort4*)&As[(it * 32 + sr) * 40 + sc] = u;
    }
#pragma unroll
    for (int it = 0; it < 2; ++it) {
      ushort4 u = {f2bf(bv2[it].x), f2bf(bv2[it].y), f2bf(bv2[it].z), f2bf(bv2[it].w)};
      *(ushort4*)&Bs[(it * 32 + sr) * 40 + sc] = u;
    }
    __syncthreads();

    bf16x8 af[4], bfr[4];
#pragma unroll
    for (int mt = 0; mt < 4; ++mt)
      af[mt] = *(bf16x8*)&As[(w * 64 + mt * 16 + ln15) * 40 + quad * 8];
#pragma unroll
    for (int nt = 0; nt < 4; ++nt)
      bfr[nt] = *(bf16x8*)&Bs[(nt * 16 + ln15) * 40 + quad * 8];
#pragma unroll
    for (int mt = 0; mt < 4; ++mt)
#pragma unroll
      for (int nt = 0; nt < 4; ++nt)
        acc[mt][nt] = __builtin_amdgcn_mfma_f32_16x16x32_bf16(
            af[mt], bfr[nt], acc[mt][nt], 0, 0, 0);
    __syncthreads();
  }

  // Epilogue.  D layout: col = ln15 (n), row = quad*4 + r (m).
#pragma unroll
  for (int nt = 0; nt < 4; ++nt) {
    const int colg = n0 + nt * 16 + ln15;
    const int s    = colg / 192;
    const int rem  = colg % 192;
    const int h    = rem >> 5;
    const int dd   = rem & 31;
    const float bias = Bv[colg];
    const float sc2  = (s == 0) ? SCALE : 1.0f;
    unsigned short* dst = (s == 0) ? qb : (s == 1 ? kb : vb);
#pragma unroll
    for (int mt = 0; mt < 4; ++mt) {
#pragma unroll
      for (int r = 0; r < 4; ++r) {
        const int m  = m0 + w * 64 + mt * 16 + quad * 4 + r;
        const int bw = m / NTOK;
        const int n  = m % NTOK;
        const unsigned short val = f2bf((acc[mt][nt][r] + bias) * sc2);
        if (s < 2)
          dst[((size_t)(bw * NH + h) * NTOK + n) * HD + dd] = val;       // [bw,h,n,d]
        else
          dst[((size_t)(bw * NH + h) * HD + dd) * NTOK + n] = val;       // [bw,h,d,n]
      }
    }
  }
}

// ---------------------------------------------------------------------------
// Kernel 2: MFMA attention.  Grid = 480*3*3 = 4320 blocks; 128 threads =
// 2 waves; wave handles head h = hp*2+wave, i-groups [gs*3, gs*3+3).
// K and V^T fragments preloaded once into registers.  No __syncthreads.
// Bias comes from the precomputed biasb (streamed, no gather chain).
// ---------------------------------------------------------------------------
__global__ __launch_bounds__(128) void attn_k(
    const unsigned short* __restrict__ qbuf, const unsigned short* __restrict__ kbuf,
    const unsigned short* __restrict__ vbuf, const float* __restrict__ mask,
    const unsigned short* __restrict__ biasb, unsigned short* __restrict__ ao) {
  __shared__ unsigned short Ps[2 * 16 * 168];

  const int t    = threadIdx.x;
  const int wave = t >> 6;
  const int lane = t & 63;
  const int ln15 = lane & 15;
  const int quad = lane >> 4;
  const int idx  = blockIdx.x;
  const int bw   = idx / 9;
  const int rem9 = idx % 9;
  const int hp   = rem9 / 3;
  const int gs   = rem9 % 3;
  const int h    = hp * 2 + wave;
  const int w    = bw & 31;
  const int wh   = w * NH + h;
  const size_t hb = (size_t)(bw * NH + h) * (NTOK * HD);
  const unsigned short* qh = qbuf + hb;
  const unsigned short* kh = kbuf + hb;
  const unsigned short* vh = vbuf + hb;           // [32][144] (transposed)
  const float* maskp = mask + (size_t)bw * NN;
  const unsigned short* biasp = biasb + (size_t)wh * NN;
  unsigned short* ps = &Ps[wave * 16 * 168];

  // zero the K-pad columns 144..159 of P (stores below never touch them)
  {
    ushort4 z = {0, 0, 0, 0};
    *(ushort4*)&ps[(lane >> 2) * 168 + 144 + (lane & 3) * 4] = z;
  }

  // Preload K fragments (B operand, n=token j, k=d).
  bf16x8 kf[9];
#pragma unroll
  for (int jt = 0; jt < 9; ++jt)
    kf[jt] = *(const bf16x8*)&kh[(jt * 16 + ln15) * HD + quad * 8];

  // Preload V^T fragments (B operand, n=d, k=token j).  kt=4 tail reads past
  // 144 — multiplied by zeroed P columns, harmless (ws has slack).
  bf16x8 vf[5][2];
#pragma unroll
  for (int kt = 0; kt < 5; ++kt)
#pragma unroll
    for (int nt = 0; nt < 2; ++nt)
      vf[kt][nt] = *(const bf16x8*)&vh[(nt * 16 + ln15) * NTOK + kt * 32 + quad * 8];

#pragma unroll
  for (int g = gs * 3; g < gs * 3 + 3; ++g) {
    const int i0 = g * 16;
    const int ib = i0 + quad * 4;

    // issue independent loads first: q frag, bias, mask
    const bf16x8 qf = *(const bf16x8*)&qh[(i0 + ln15) * HD + quad * 8];
    float bm[9][4];
#pragma unroll
    for (int jt = 0; jt < 9; ++jt) {
      const int j = jt * 16 + ln15;
#pragma unroll
      for (int r = 0; r < 4; ++r) {
        const int ij = (ib + r) * NTOK + j;
        bm[jt][r] = bf2f(biasp[ij]) + maskp[ij];
      }
    }

    // S = Q K^T  (9 n-tiles)
    f32x4 s[9];
#pragma unroll
    for (int jt = 0; jt < 9; ++jt) {
      s[jt] = (f32x4){0.f, 0.f, 0.f, 0.f};
      s[jt] = __builtin_amdgcn_mfma_f32_16x16x32_bf16(qf, kf[jt], s[jt], 0, 0, 0);
#pragma unroll
      for (int r = 0; r < 4; ++r) s[jt][r] += bm[jt][r];
    }

    // softmax over j (row = ib+r lives in the 16-lane ln15 group)
    float rinv[4];
#pragma unroll
    for (int r = 0; r < 4; ++r) {
      float mx = s[0][r];
#pragma unroll
      for (int jt = 1; jt < 9; ++jt) mx = fmaxf(mx, s[jt][r]);
#pragma unroll
      for (int off = 1; off < 16; off <<= 1) mx = fmaxf(mx, __shfl_xor(mx, off));
      float sum = 0.f;
#pragma unroll
      for (int jt = 0; jt < 9; ++jt) {
        const float e = __expf(s[jt][r] - mx);
        s[jt][r] = e;
        sum += e;
      }
#pragma unroll
      for (int off = 1; off < 16; off <<= 1) sum += __shfl_xor(sum, off);
      rinv[r] = 1.0f / sum;
    }

    // P: C-layout -> LDS -> A-layout (wave-internal, in-order DS pipe)
#pragma unroll
    for (int jt = 0; jt < 9; ++jt)
#pragma unroll
      for (int r = 0; r < 4; ++r)
        ps[(quad * 4 + r) * 168 + jt * 16 + ln15] = f2bf(s[jt][r]);

    // O = P V   (K padded to 160)
    f32x4 o[2] = {{0.f, 0.f, 0.f, 0.f}, {0.f, 0.f, 0.f, 0.f}};
#pragma unroll
    for (int kt = 0; kt < 5; ++kt) {
      const bf16x8 pf = *(const bf16x8*)&ps[ln15 * 168 + kt * 32 + quad * 8];
#pragma unroll
      for (int nt = 0; nt < 2; ++nt)
        o[nt] = __builtin_amdgcn_mfma_f32_16x16x32_bf16(pf, vf[kt][nt], o[nt], 0, 0, 0);
    }

    // store O (bf16) into [m=bw*144+i][c=h*32+d]
#pragma unroll
    for (int nt = 0; nt < 2; ++nt)
#pragma unroll
      for (int r = 0; r < 4; ++r)
        ao[(size_t)(bw * NTOK + ib + r) * DIM + h * HD + nt * 16 + ln15] =
            f2bf(o[nt][r] * rinv[r]);
  }
}

// ---------------------------------------------------------------------------
// Kernel 3: proj GEMM. A = bf16 attention output, B = fp32 weights.
// ---------------------------------------------------------------------------
__global__ __launch_bounds__(256) void proj_gemm_k(
    const unsigned short* __restrict__ AO, const float* __restrict__ W,
    const float* __restrict__ Bv, float* __restrict__ out) {
  __shared__ unsigned short As[256 * 40];
  __shared__ unsigned short Bs[64 * 40];
  const int t    = threadIdx.x;
  const int n0   = blockIdx.x * 64;
  const int m0   = blockIdx.y * 256;
  const int w    = t >> 6;
  const int lane = t & 63;
  const int ln15 = lane & 15;
  const int quad = lane >> 4;
  const int sr   = t >> 3;
  const int sc   = (t & 7) * 4;
  const int arow = t >> 2;        // 0..63
  const int acol = (t & 3) * 8;   // 0,8,16,24

  f32x4 acc[4][4];
#pragma unroll
  for (int i = 0; i < 4; ++i)
#pragma unroll
    for (int j = 0; j < 4; ++j) acc[i][j] = (f32x4){0.f, 0.f, 0.f, 0.f};

  for (int k0 = 0; k0 < 192; k0 += 32) {
    u16x8 av[4];
#pragma unroll
    for (int it = 0; it < 4; ++it)
      av[it] = *(const u16x8*)(AO + (size_t)(m0 + it * 64 + arow) * 192 + k0 + acol);
    float4 bv2[2];
#pragma unroll
    for (int it = 0; it < 2; ++it)
      bv2[it] = *(const float4*)(W + (size_t)(n0 + it * 32 + sr) * 192 + k0 + sc);
    __syncthreads();
#pragma unroll
    for (int it = 0; it < 4; ++it)
      *(u16x8*)&As[(it * 64 + arow) * 40 + acol] = av[it];
#pragma unroll
    for (int it = 0; it < 2; ++it) {
      ushort4 u = {f2bf(bv2[it].x), f2bf(bv2[it].y), f2bf(bv2[it].z), f2bf(bv2[it].w)};
      *(ushort4*)&Bs[(it * 32 + sr) * 40 + sc] = u;
    }
    __syncthreads();

    bf16x8 af[4], bfr[4];
#pragma unroll
    for (int mt = 0; mt < 4; ++mt)
      af[mt] = *(bf16x8*)&As[(w * 64 + mt * 16 + ln15) * 40 + quad * 8];
#pragma unroll
    for (int nt = 0; nt < 4; ++nt)
      bfr[nt] = *(bf16x8*)&Bs[(nt * 16 + ln15) * 40 + quad * 8];
#pragma unroll
    for (int mt = 0; mt < 4; ++mt)
#pragma unroll
      for (int nt = 0; nt < 4; ++nt)
        acc[mt][nt] = __builtin_amdgcn_mfma_f32_16x16x32_bf16(
            af[mt], bfr[nt], acc[mt][nt], 0, 0, 0);
    __syncthreads();
  }

#pragma unroll
  for (int nt = 0; nt < 4; ++nt) {
    const int colg = n0 + nt * 16 + ln15;
    const float bias = Bv[colg];
#pragma unroll
    for (int mt = 0; mt < 4; ++mt) {
#pragma unroll
      for (int r = 0; r < 4; ++r) {
        const int m = m0 + w * 64 + mt * 16 + quad * 4 + r;
        out[(size_t)m * 192 + colg] = acc[mt][nt][r] + bias;
      }
    }
  }
}

// ---------------------------------------------------------------------------
extern "C" void kernel_launch(void* const* d_in, const int* in_sizes, int n_in,
                              void* d_out, int out_size, void* d_ws, size_t ws_size,
                              hipStream_t stream) {
  const float* x      = (const float*)d_in[0];
  const float* mask   = (const float*)d_in[1];
  const float* qkv_w  = (const float*)d_in[2];
  const float* qkv_b  = (const float*)d_in[3];
  const float* proj_w = (const float*)d_in[4];
  const float* proj_b = (const float*)d_in[5];
  const float* btab   = (const float*)d_in[6];
  const int*   pos    = (const int*)d_in[7];
  float* out = (float*)d_out;

  unsigned short* ws = (unsigned short*)d_ws;
  const size_t sz = (size_t)MROWS * DIM;   // 13,271,040 elements
  unsigned short* qbuf  = ws;
  unsigned short* kbuf  = ws + sz;
  unsigned short* vbuf  = ws + 2 * sz;
  unsigned short* aobuf = ws + 3 * sz + 256;            // slack for V^T tail reads
  unsigned short* biasb = ws + 4 * sz + 1024;           // 192*20736 bf16 = 8 MB

  bias_pre_k<<<dim3(NW * NH, 9), 256, 0, stream>>>(btab, pos, biasb);
  qkv_gemm_k<<<dim3(K3 / 64, MROWS / 256), 256, 0, stream>>>(
      x, qkv_w, qkv_b, qbuf, kbuf, vbuf);
  attn_k<<<B_LON * NW * 9, 128, 0, stream>>>(
      qbuf, kbuf, vbuf, mask, biasb, aobuf);
  proj_gemm_k<<<dim3(DIM / 64, MROWS / 256), 256, 0, stream>>>(
      aobuf, proj_w, proj_b, out);
}

// Round 5
// 376.240 us; speedup vs baseline: 1.9722x; 1.0799x over previous
//
#include <hip/hip_runtime.h>
#include <hip/hip_bf16.h>

// Problem constants
#define B_LON 15      // NLON
#define NW    32      // TYPE_OF_WINDOWS
#define NTOK  144     // N_TOK
#define DIM   192
#define NH    6
#define HD    32
#define K3    576     // 3*DIM
#define MROWS (B_LON*NW*NTOK)   // 69120
#define NN    (NTOK*NTOK)       // 20736
#define SCALE 0.17677669529663687f  // 32^-0.5

typedef __attribute__((ext_vector_type(8))) short bf16x8;
typedef __attribute__((ext_vector_type(8))) unsigned short u16x8;
typedef __attribute__((ext_vector_type(4))) float f32x4;

__device__ inline unsigned short f2bf(float f) {
  __bf16 h = (__bf16)f;
  return __builtin_bit_cast(unsigned short, h);
}
__device__ inline float bf2f(unsigned short u) {
  union { unsigned int i; float f; } c;
  c.i = ((unsigned int)u) << 16;
  return c.f;
}

// element-octet counts for the convert kernel
#define NX8 1658880   // 69120*192/8
#define NQ8 13824     // 576*192/8
#define NP8 4608      // 192*192/8

// ---------------------------------------------------------------------------
// Kernel -1: fp32 -> bf16 pre-convert of x, qkv_w, proj_w.
// ---------------------------------------------------------------------------
__global__ __launch_bounds__(256) void conv_bf_k(
    const float* __restrict__ x, const float* __restrict__ qw,
    const float* __restrict__ pw,
    unsigned short* __restrict__ xbf, unsigned short* __restrict__ qwbf,
    unsigned short* __restrict__ pwbf) {
  const long gid = (long)blockIdx.x * 256 + threadIdx.x;
  const float* src;
  unsigned short* dst;
  long off;
  if (gid < NX8)            { src = x;  dst = xbf;  off = gid; }
  else if (gid < NX8 + NQ8) { src = qw; dst = qwbf; off = gid - NX8; }
  else                      { src = pw; dst = pwbf; off = gid - NX8 - NQ8; }
  const float4 a = ((const float4*)src)[off * 2];
  const float4 b = ((const float4*)src)[off * 2 + 1];
  u16x8 u = {f2bf(a.x), f2bf(a.y), f2bf(a.z), f2bf(a.w),
             f2bf(b.x), f2bf(b.y), f2bf(b.z), f2bf(b.w)};
  *(u16x8*)&dst[off * 8] = u;
}

// ---------------------------------------------------------------------------
// Kernel 0: bias precompute.  biasb[wh][ij] = bf16(btab[pos[ij]*192 + wh]).
// ---------------------------------------------------------------------------
__global__ __launch_bounds__(256) void bias_pre_k(
    const float* __restrict__ btab, const int* __restrict__ pos,
    unsigned short* __restrict__ biasb) {
  const int wh  = blockIdx.x;          // 0..191
  const int seg = blockIdx.y * 2304;   // 9 segs of 2304
  unsigned short* dst = biasb + (size_t)wh * NN;
#pragma unroll
  for (int it = 0; it < 9; ++it) {
    const int e = seg + it * 256 + threadIdx.x;
    dst[e] = f2bf(btab[(size_t)pos[e] * (NW * NH) + wh]);
  }
}

// ---------------------------------------------------------------------------
// Kernel 1: QKV GEMM, all-bf16 staging.  M=69120, N=576, K=192, BK=64.
// Tile 256x64, 256 threads = 4 waves, each wave 64x64 via 4x4 16x16x32 MFMA.
// LDS stride 72 shorts (144B): frag-read banks = (ln15+quad)*4 mod 32 ->
// uniform 8 accesses/bank for b128 (conflict-neutral).
// Epilogue: q(scaled),k -> [bw,h,n,d]; v -> [bw,h,d,n] (transposed).
// ---------------------------------------------------------------------------
__global__ __launch_bounds__(256) void qkv_gemm_k(
    const unsigned short* __restrict__ X, const unsigned short* __restrict__ W,
    const float* __restrict__ Bv,
    unsigned short* __restrict__ qb, unsigned short* __restrict__ kb,
    unsigned short* __restrict__ vb) {
  __shared__ unsigned short As[256 * 72];
  __shared__ unsigned short Bs[64 * 72];
  const int t    = threadIdx.x;
  const int n0   = blockIdx.x * 64;
  const int m0   = blockIdx.y * 256;
  const int w    = t >> 6;
  const int lane = t & 63;
  const int ln15 = lane & 15;
  const int quad = lane >> 4;
  const int srow = t >> 3;        // 0..31
  const int schk = (t & 7) * 8;   // col offset in shorts

  f32x4 acc[4][4];
#pragma unroll
  for (int i = 0; i < 4; ++i)
#pragma unroll
    for (int j = 0; j < 4; ++j) acc[i][j] = (f32x4){0.f, 0.f, 0.f, 0.f};

  for (int k0 = 0; k0 < 192; k0 += 64) {
    u16x8 ar[8], br[2];
#pragma unroll
    for (int rr = 0; rr < 8; ++rr)
      ar[rr] = *(const u16x8*)&X[(size_t)(m0 + rr * 32 + srow) * 192 + k0 + schk];
#pragma unroll
    for (int rr = 0; rr < 2; ++rr)
      br[rr] = *(const u16x8*)&W[(size_t)(n0 + rr * 32 + srow) * 192 + k0 + schk];
    __syncthreads();
#pragma unroll
    for (int rr = 0; rr < 8; ++rr)
      *(u16x8*)&As[(rr * 32 + srow) * 72 + schk] = ar[rr];
#pragma unroll
    for (int rr = 0; rr < 2; ++rr)
      *(u16x8*)&Bs[(rr * 32 + srow) * 72 + schk] = br[rr];
    __syncthreads();

#pragma unroll
    for (int half = 0; half < 2; ++half) {
      bf16x8 af[4], bf[4];
#pragma unroll
      for (int mt = 0; mt < 4; ++mt)
        af[mt] = *(bf16x8*)&As[(w * 64 + mt * 16 + ln15) * 72 + half * 32 + quad * 8];
#pragma unroll
      for (int nt = 0; nt < 4; ++nt)
        bf[nt] = *(bf16x8*)&Bs[(nt * 16 + ln15) * 72 + half * 32 + quad * 8];
#pragma unroll
      for (int mt = 0; mt < 4; ++mt)
#pragma unroll
        for (int nt = 0; nt < 4; ++nt)
          acc[mt][nt] = __builtin_amdgcn_mfma_f32_16x16x32_bf16(
              af[mt], bf[nt], acc[mt][nt], 0, 0, 0);
    }
    __syncthreads();
  }

  // Epilogue.  s is block-uniform (n0 multiple of 64, 192=3*64).
  const int s   = n0 / 192;
  const int nr  = n0 % 192;
  const float sc2 = (s == 0) ? SCALE : 1.0f;
  unsigned short* dst = (s == 0) ? qb : (s == 1 ? kb : vb);
#pragma unroll
  for (int nt = 0; nt < 4; ++nt) {
    const int colg = n0 + nt * 16 + ln15;
    const int h    = (nr + nt * 16 + ln15) >> 5;
    const int dd   = (nr + nt * 16 + ln15) & 31;
    const float bias = Bv[colg];
#pragma unroll
    for (int mt = 0; mt < 4; ++mt) {
#pragma unroll
      for (int r = 0; r < 4; ++r) {
        const int m  = m0 + w * 64 + mt * 16 + quad * 4 + r;
        const int bw = m / NTOK;
        const int n  = m % NTOK;
        const unsigned short val = f2bf((acc[mt][nt][r] + bias) * sc2);
        if (s < 2)
          dst[((size_t)(bw * NH + h) * NTOK + n) * HD + dd] = val;   // [bw,h,n,d]
        else
          dst[((size_t)(bw * NH + h) * HD + dd) * NTOK + n] = val;   // [bw,h,d,n]
      }
    }
  }
}

// ---------------------------------------------------------------------------
// Kernel 2: MFMA attention (unchanged from R4).
// ---------------------------------------------------------------------------
__global__ __launch_bounds__(128) void attn_k(
    const unsigned short* __restrict__ qbuf, const unsigned short* __restrict__ kbuf,
    const unsigned short* __restrict__ vbuf, const float* __restrict__ mask,
    const unsigned short* __restrict__ biasb, unsigned short* __restrict__ ao) {
  __shared__ unsigned short Ps[2 * 16 * 168];

  const int t    = threadIdx.x;
  const int wave = t >> 6;
  const int lane = t & 63;
  const int ln15 = lane & 15;
  const int quad = lane >> 4;
  const int idx  = blockIdx.x;
  const int bw   = idx / 9;
  const int rem9 = idx % 9;
  const int hp   = rem9 / 3;
  const int gs   = rem9 % 3;
  const int h    = hp * 2 + wave;
  const int w    = bw & 31;
  const int wh   = w * NH + h;
  const size_t hb = (size_t)(bw * NH + h) * (NTOK * HD);
  const unsigned short* qh = qbuf + hb;
  const unsigned short* kh = kbuf + hb;
  const unsigned short* vh = vbuf + hb;           // [32][144] (transposed)
  const float* maskp = mask + (size_t)bw * NN;
  const unsigned short* biasp = biasb + (size_t)wh * NN;
  unsigned short* ps = &Ps[wave * 16 * 168];

  {
    ushort4 z = {0, 0, 0, 0};
    *(ushort4*)&ps[(lane >> 2) * 168 + 144 + (lane & 3) * 4] = z;
  }

  bf16x8 kf[9];
#pragma unroll
  for (int jt = 0; jt < 9; ++jt)
    kf[jt] = *(const bf16x8*)&kh[(jt * 16 + ln15) * HD + quad * 8];

  bf16x8 vf[5][2];
#pragma unroll
  for (int kt = 0; kt < 5; ++kt)
#pragma unroll
    for (int nt = 0; nt < 2; ++nt)
      vf[kt][nt] = *(const bf16x8*)&vh[(nt * 16 + ln15) * NTOK + kt * 32 + quad * 8];

#pragma unroll
  for (int g = gs * 3; g < gs * 3 + 3; ++g) {
    const int i0 = g * 16;
    const int ib = i0 + quad * 4;

    const bf16x8 qf = *(const bf16x8*)&qh[(i0 + ln15) * HD + quad * 8];
    float bm[9][4];
#pragma unroll
    for (int jt = 0; jt < 9; ++jt) {
      const int j = jt * 16 + ln15;
#pragma unroll
      for (int r = 0; r < 4; ++r) {
        const int ij = (ib + r) * NTOK + j;
        bm[jt][r] = bf2f(biasp[ij]) + maskp[ij];
      }
    }

    f32x4 s[9];
#pragma unroll
    for (int jt = 0; jt < 9; ++jt) {
      s[jt] = (f32x4){0.f, 0.f, 0.f, 0.f};
      s[jt] = __builtin_amdgcn_mfma_f32_16x16x32_bf16(qf, kf[jt], s[jt], 0, 0, 0);
#pragma unroll
      for (int r = 0; r < 4; ++r) s[jt][r] += bm[jt][r];
    }

    float rinv[4];
#pragma unroll
    for (int r = 0; r < 4; ++r) {
      float mx = s[0][r];
#pragma unroll
      for (int jt = 1; jt < 9; ++jt) mx = fmaxf(mx, s[jt][r]);
#pragma unroll
      for (int off = 1; off < 16; off <<= 1) mx = fmaxf(mx, __shfl_xor(mx, off));
      float sum = 0.f;
#pragma unroll
      for (int jt = 0; jt < 9; ++jt) {
        const float e = __expf(s[jt][r] - mx);
        s[jt][r] = e;
        sum += e;
      }
#pragma unroll
      for (int off = 1; off < 16; off <<= 1) sum += __shfl_xor(sum, off);
      rinv[r] = 1.0f / sum;
    }

#pragma unroll
    for (int jt = 0; jt < 9; ++jt)
#pragma unroll
      for (int r = 0; r < 4; ++r)
        ps[(quad * 4 + r) * 168 + jt * 16 + ln15] = f2bf(s[jt][r]);

    f32x4 o[2] = {{0.f, 0.f, 0.f, 0.f}, {0.f, 0.f, 0.f, 0.f}};
#pragma unroll
    for (int kt = 0; kt < 5; ++kt) {
      const bf16x8 pf = *(const bf16x8*)&ps[ln15 * 168 + kt * 32 + quad * 8];
#pragma unroll
      for (int nt = 0; nt < 2; ++nt)
        o[nt] = __builtin_amdgcn_mfma_f32_16x16x32_bf16(pf, vf[kt][nt], o[nt], 0, 0, 0);
    }

#pragma unroll
    for (int nt = 0; nt < 2; ++nt)
#pragma unroll
      for (int r = 0; r < 4; ++r)
        ao[(size_t)(bw * NTOK + ib + r) * DIM + h * HD + nt * 16 + ln15] =
            f2bf(o[nt][r] * rinv[r]);
  }
}

// ---------------------------------------------------------------------------
// Kernel 3: proj GEMM, all-bf16 staging.  M=69120, N=192, K=192, BK=64.
// ---------------------------------------------------------------------------
__global__ __launch_bounds__(256) void proj_gemm_k(
    const unsigned short* __restrict__ AO, const unsigned short* __restrict__ W,
    const float* __restrict__ Bv, float* __restrict__ out) {
  __shared__ unsigned short As[256 * 72];
  __shared__ unsigned short Bs[64 * 72];
  const int t    = threadIdx.x;
  const int n0   = blockIdx.x * 64;
  const int m0   = blockIdx.y * 256;
  const int w    = t >> 6;
  const int lane = t & 63;
  const int ln15 = lane & 15;
  const int quad = lane >> 4;
  const int srow = t >> 3;
  const int schk = (t & 7) * 8;

  f32x4 acc[4][4];
#pragma unroll
  for (int i = 0; i < 4; ++i)
#pragma unroll
    for (int j = 0; j < 4; ++j) acc[i][j] = (f32x4){0.f, 0.f, 0.f, 0.f};

  for (int k0 = 0; k0 < 192; k0 += 64) {
    u16x8 ar[8], br[2];
#pragma unroll
    for (int rr = 0; rr < 8; ++rr)
      ar[rr] = *(const u16x8*)&AO[(size_t)(m0 + rr * 32 + srow) * 192 + k0 + schk];
#pragma unroll
    for (int rr = 0; rr < 2; ++rr)
      br[rr] = *(const u16x8*)&W[(size_t)(n0 + rr * 32 + srow) * 192 + k0 + schk];
    __syncthreads();
#pragma unroll
    for (int rr = 0; rr < 8; ++rr)
      *(u16x8*)&As[(rr * 32 + srow) * 72 + schk] = ar[rr];
#pragma unroll
    for (int rr = 0; rr < 2; ++rr)
      *(u16x8*)&Bs[(rr * 32 + srow) * 72 + schk] = br[rr];
    __syncthreads();

#pragma unroll
    for (int half = 0; half < 2; ++half) {
      bf16x8 af[4], bf[4];
#pragma unroll
      for (int mt = 0; mt < 4; ++mt)
        af[mt] = *(bf16x8*)&As[(w * 64 + mt * 16 + ln15) * 72 + half * 32 + quad * 8];
#pragma unroll
      for (int nt = 0; nt < 4; ++nt)
        bf[nt] = *(bf16x8*)&Bs[(nt * 16 + ln15) * 72 + half * 32 + quad * 8];
#pragma unroll
      for (int mt = 0; mt < 4; ++mt)
#pragma unroll
        for (int nt = 0; nt < 4; ++nt)
          acc[mt][nt] = __builtin_amdgcn_mfma_f32_16x16x32_bf16(
              af[mt], bf[nt], acc[mt][nt], 0, 0, 0);
    }
    __syncthreads();
  }

#pragma unroll
  for (int nt = 0; nt < 4; ++nt) {
    const int colg = n0 + nt * 16 + ln15;
    const float bias = Bv[colg];
#pragma unroll
    for (int mt = 0; mt < 4; ++mt) {
#pragma unroll
      for (int r = 0; r < 4; ++r) {
        const int m = m0 + w * 64 + mt * 16 + quad * 4 + r;
        out[(size_t)m * 192 + colg] = acc[mt][nt][r] + bias;
      }
    }
  }
}

// ---------------------------------------------------------------------------
extern "C" void kernel_launch(void* const* d_in, const int* in_sizes, int n_in,
                              void* d_out, int out_size, void* d_ws, size_t ws_size,
                              hipStream_t stream) {
  const float* x      = (const float*)d_in[0];
  const float* mask   = (const float*)d_in[1];
  const float* qkv_w  = (const float*)d_in[2];
  const float* qkv_b  = (const float*)d_in[3];
  const float* proj_w = (const float*)d_in[4];
  const float* proj_b = (const float*)d_in[5];
  const float* btab   = (const float*)d_in[6];
  const int*   pos    = (const int*)d_in[7];
  float* out = (float*)d_out;

  unsigned short* ws = (unsigned short*)d_ws;
  const size_t sz = (size_t)MROWS * DIM;   // 13,271,040 elements
  unsigned short* qbuf  = ws;
  unsigned short* kbuf  = ws + sz;
  unsigned short* vbuf  = ws + 2 * sz;
  unsigned short* aobuf = ws + 3 * sz + 256;            // slack for V^T tail reads
  unsigned short* biasb = ws + 4 * sz + 1024;           // 192*20736 bf16 = 8 MB
  unsigned short* xbf   = biasb + (size_t)192 * NN;     // 26.5 MB
  unsigned short* qwbf  = xbf + sz;
  unsigned short* pwbf  = qwbf + (size_t)K3 * DIM;

  conv_bf_k<<<NX8 / 256 + NQ8 / 256 + NP8 / 256, 256, 0, stream>>>(
      x, qkv_w, proj_w, xbf, qwbf, pwbf);
  bias_pre_k<<<dim3(NW * NH, 9), 256, 0, stream>>>(btab, pos, biasb);
  qkv_gemm_k<<<dim3(K3 / 64, MROWS / 256), 256, 0, stream>>>(
      xbf, qwbf, qkv_b, qbuf, kbuf, vbuf);
  attn_k<<<B_LON * NW * 9, 128, 0, stream>>>(
      qbuf, kbuf, vbuf, mask, biasb, aobuf);
  proj_gemm_k<<<dim3(DIM / 64, MROWS / 256), 256, 0, stream>>>(
      aobuf, pwbf, proj_b, out);
}

// Round 6
// 304.513 us; speedup vs baseline: 2.4367x; 1.2355x over previous
//
#include <hip/hip_runtime.h>
#include <hip/hip_bf16.h>

// Problem constants
#define B_LON 15      // NLON
#define NW    32      // TYPE_OF_WINDOWS
#define NTOK  144     // N_TOK
#define DIM   192
#define NH    6
#define HD    32
#define K3    576     // 3*DIM
#define MROWS (B_LON*NW*NTOK)   // 69120
#define NN    (NTOK*NTOK)       // 20736
#define SCALE 0.17677669529663687f  // 32^-0.5

typedef __attribute__((ext_vector_type(8))) short bf16x8;
typedef __attribute__((ext_vector_type(8))) unsigned short u16x8;
typedef __attribute__((ext_vector_type(4))) float f32x4;

__device__ inline unsigned short f2bf(float f) {
  __bf16 h = (__bf16)f;
  return __builtin_bit_cast(unsigned short, h);
}
__device__ inline float bf2f(unsigned short u) {
  union { unsigned int i; float f; } c;
  c.i = ((unsigned int)u) << 16;
  return c.f;
}

// element-octet counts for the convert kernel
#define NX8 1658880   // 69120*192/8
#define NQ8 13824     // 576*192/8
#define NP8 4608      // 192*192/8

// ---------------------------------------------------------------------------
// Kernel -1: fp32 -> bf16 pre-convert of x, qkv_w, proj_w.
// ---------------------------------------------------------------------------
__global__ __launch_bounds__(256) void conv_bf_k(
    const float* __restrict__ x, const float* __restrict__ qw,
    const float* __restrict__ pw,
    unsigned short* __restrict__ xbf, unsigned short* __restrict__ qwbf,
    unsigned short* __restrict__ pwbf) {
  const long gid = (long)blockIdx.x * 256 + threadIdx.x;
  const float* src;
  unsigned short* dst;
  long off;
  if (gid < NX8)            { src = x;  dst = xbf;  off = gid; }
  else if (gid < NX8 + NQ8) { src = qw; dst = qwbf; off = gid - NX8; }
  else                      { src = pw; dst = pwbf; off = gid - NX8 - NQ8; }
  const float4 a = ((const float4*)src)[off * 2];
  const float4 b = ((const float4*)src)[off * 2 + 1];
  u16x8 u = {f2bf(a.x), f2bf(a.y), f2bf(a.z), f2bf(a.w),
             f2bf(b.x), f2bf(b.y), f2bf(b.z), f2bf(b.w)};
  *(u16x8*)&dst[off * 8] = u;
}

// ---------------------------------------------------------------------------
// Kernel 0: bias precompute.  biasb[wh][ij] = bf16(btab[pos[ij]*192 + wh]).
// ---------------------------------------------------------------------------
__global__ __launch_bounds__(256) void bias_pre_k(
    const float* __restrict__ btab, const int* __restrict__ pos,
    unsigned short* __restrict__ biasb) {
  const int wh  = blockIdx.x;          // 0..191
  const int seg = blockIdx.y * 2304;   // 9 segs of 2304
  unsigned short* dst = biasb + (size_t)wh * NN;
#pragma unroll
  for (int it = 0; it < 9; ++it) {
    const int e = seg + it * 256 + threadIdx.x;
    dst[e] = f2bf(btab[(size_t)pos[e] * (NW * NH) + wh]);
  }
}

// ---------------------------------------------------------------------------
// Kernel 1: QKV GEMM, all-bf16 staging (unchanged from R5).
// ---------------------------------------------------------------------------
__global__ __launch_bounds__(256) void qkv_gemm_k(
    const unsigned short* __restrict__ X, const unsigned short* __restrict__ W,
    const float* __restrict__ Bv,
    unsigned short* __restrict__ qb, unsigned short* __restrict__ kb,
    unsigned short* __restrict__ vb) {
  __shared__ unsigned short As[256 * 72];
  __shared__ unsigned short Bs[64 * 72];
  const int t    = threadIdx.x;
  const int n0   = blockIdx.x * 64;
  const int m0   = blockIdx.y * 256;
  const int w    = t >> 6;
  const int lane = t & 63;
  const int ln15 = lane & 15;
  const int quad = lane >> 4;
  const int srow = t >> 3;
  const int schk = (t & 7) * 8;

  f32x4 acc[4][4];
#pragma unroll
  for (int i = 0; i < 4; ++i)
#pragma unroll
    for (int j = 0; j < 4; ++j) acc[i][j] = (f32x4){0.f, 0.f, 0.f, 0.f};

  for (int k0 = 0; k0 < 192; k0 += 64) {
    u16x8 ar[8], br[2];
#pragma unroll
    for (int rr = 0; rr < 8; ++rr)
      ar[rr] = *(const u16x8*)&X[(size_t)(m0 + rr * 32 + srow) * 192 + k0 + schk];
#pragma unroll
    for (int rr = 0; rr < 2; ++rr)
      br[rr] = *(const u16x8*)&W[(size_t)(n0 + rr * 32 + srow) * 192 + k0 + schk];
    __syncthreads();
#pragma unroll
    for (int rr = 0; rr < 8; ++rr)
      *(u16x8*)&As[(rr * 32 + srow) * 72 + schk] = ar[rr];
#pragma unroll
    for (int rr = 0; rr < 2; ++rr)
      *(u16x8*)&Bs[(rr * 32 + srow) * 72 + schk] = br[rr];
    __syncthreads();

#pragma unroll
    for (int half = 0; half < 2; ++half) {
      bf16x8 af[4], bf[4];
#pragma unroll
      for (int mt = 0; mt < 4; ++mt)
        af[mt] = *(bf16x8*)&As[(w * 64 + mt * 16 + ln15) * 72 + half * 32 + quad * 8];
#pragma unroll
      for (int nt = 0; nt < 4; ++nt)
        bf[nt] = *(bf16x8*)&Bs[(nt * 16 + ln15) * 72 + half * 32 + quad * 8];
#pragma unroll
      for (int mt = 0; mt < 4; ++mt)
#pragma unroll
        for (int nt = 0; nt < 4; ++nt)
          acc[mt][nt] = __builtin_amdgcn_mfma_f32_16x16x32_bf16(
              af[mt], bf[nt], acc[mt][nt], 0, 0, 0);
    }
    __syncthreads();
  }

  const int s   = n0 / 192;
  const int nr  = n0 % 192;
  const float sc2 = (s == 0) ? SCALE : 1.0f;
  unsigned short* dst = (s == 0) ? qb : (s == 1 ? kb : vb);
#pragma unroll
  for (int nt = 0; nt < 4; ++nt) {
    const int colg = n0 + nt * 16 + ln15;
    const int h    = (nr + nt * 16 + ln15) >> 5;
    const int dd   = (nr + nt * 16 + ln15) & 31;
    const float bias = Bv[colg];
#pragma unroll
    for (int mt = 0; mt < 4; ++mt) {
#pragma unroll
      for (int r = 0; r < 4; ++r) {
        const int m  = m0 + w * 64 + mt * 16 + quad * 4 + r;
        const int bw = m / NTOK;
        const int n  = m % NTOK;
        const unsigned short val = f2bf((acc[mt][nt][r] + bias) * sc2);
        if (s < 2)
          dst[((size_t)(bw * NH + h) * NTOK + n) * HD + dd] = val;   // [bw,h,n,d]
        else
          dst[((size_t)(bw * NH + h) * HD + dd) * NTOK + n] = val;   // [bw,h,d,n]
      }
    }
  }
}

// ---------------------------------------------------------------------------
// Kernel 2: MFMA attention, LDS-resident K/V (no register preload, no spills).
// Grid: 2880 blocks; block = (bw, h) with h = idx/480, bw = idx%480 so blocks
// sharing mask (same bw) / bias (same w,h) sit 480 = 0 mod 8 apart -> same XCD.
// 192 threads = 3 waves; wave handles i-groups [3*wave, 3*wave+3).
// One __syncthreads after staging; P round-trip is per-wave.
// ---------------------------------------------------------------------------
__global__ __launch_bounds__(192, 3) void attn_k(
    const unsigned short* __restrict__ qbuf, const unsigned short* __restrict__ kbuf,
    const unsigned short* __restrict__ vbuf, const float* __restrict__ mask,
    const unsigned short* __restrict__ biasb, unsigned short* __restrict__ ao) {
  __shared__ unsigned short Ks[NTOK * 36];     // K  [144][32] @ stride 36
  __shared__ unsigned short Vs[32 * 160];      // V^T [32][144] @ stride 160, cols 144..159 zero
  __shared__ unsigned short Ps[3 * 16 * 168];  // per-wave P

  const int t    = threadIdx.x;
  const int wave = t / 64;
  const int lane = t & 63;
  const int ln15 = lane & 15;
  const int quad = lane >> 4;
  const int idx  = blockIdx.x;
  const int h    = idx / 480;
  const int bw   = idx % 480;
  const int w    = bw & 31;
  const int wh   = w * NH + h;
  const size_t hb = (size_t)(bw * NH + h) * (NTOK * HD);
  const unsigned short* qh = qbuf + hb;
  const float* maskp = mask + (size_t)bw * NN;
  const unsigned short* biasp = biasb + (size_t)wh * NN;
  unsigned short* ps = &Ps[wave * 16 * 168];

  // stage K: 144 rows x 4 u16x8
  for (int it = t; it < 576; it += 192) {
    const int row = it >> 2;
    const int col = (it & 3) * 8;
    *(u16x8*)&Ks[row * 36 + col] = *(const u16x8*)&kbuf[hb + row * HD + col];
  }
  // stage V^T: 32 rows x 18 u16x8
  for (int it = t; it < 576; it += 192) {
    const int row = it / 18;
    const int col = (it % 18) * 8;
    *(u16x8*)&Vs[row * 160 + col] = *(const u16x8*)&vbuf[hb + row * NTOK + col];
  }
  // zero V pad cols 144..159
  if (t < 64) {
    u16x8 z = {0, 0, 0, 0, 0, 0, 0, 0};
    *(u16x8*)&Vs[(t >> 1) * 160 + 144 + (t & 1) * 8] = z;
  }
  // zero P pad cols 144..159 (per wave)
  {
    ushort4 z = {0, 0, 0, 0};
    *(ushort4*)&ps[(lane >> 2) * 168 + 144 + (lane & 3) * 4] = z;
  }
  __syncthreads();

  for (int g = wave * 3; g < wave * 3 + 3; ++g) {
    const int i0 = g * 16;
    const int ib = i0 + quad * 4;

    // S = Q K^T  (A-frag from global, B-frags from LDS)
    const bf16x8 qf = *(const bf16x8*)&qh[(i0 + ln15) * HD + quad * 8];
    f32x4 s[9];
#pragma unroll
    for (int jt = 0; jt < 9; ++jt) {
      const bf16x8 kf = *(const bf16x8*)&Ks[(jt * 16 + ln15) * 36 + quad * 8];
      s[jt] = (f32x4){0.f, 0.f, 0.f, 0.f};
      s[jt] = __builtin_amdgcn_mfma_f32_16x16x32_bf16(qf, kf, s[jt], 0, 0, 0);
    }

    // + bias + mask (streamed, independent loads)
#pragma unroll
    for (int jt = 0; jt < 9; ++jt) {
      const int j = jt * 16 + ln15;
#pragma unroll
      for (int r = 0; r < 4; ++r) {
        const int ij = (ib + r) * NTOK + j;
        s[jt][r] += bf2f(biasp[ij]) + maskp[ij];
      }
    }

    // softmax over j (row = ib+r lives in the 16-lane ln15 group)
    float rinv[4];
#pragma unroll
    for (int r = 0; r < 4; ++r) {
      float mx = s[0][r];
#pragma unroll
      for (int jt = 1; jt < 9; ++jt) mx = fmaxf(mx, s[jt][r]);
#pragma unroll
      for (int off = 1; off < 16; off <<= 1) mx = fmaxf(mx, __shfl_xor(mx, off));
      float sum = 0.f;
#pragma unroll
      for (int jt = 0; jt < 9; ++jt) {
        const float e = __expf(s[jt][r] - mx);
        s[jt][r] = e;
        sum += e;
      }
#pragma unroll
      for (int off = 1; off < 16; off <<= 1) sum += __shfl_xor(sum, off);
      rinv[r] = 1.0f / sum;
    }

    // P: C-layout -> LDS -> A-layout (wave-internal)
#pragma unroll
    for (int jt = 0; jt < 9; ++jt)
#pragma unroll
      for (int r = 0; r < 4; ++r)
        ps[(quad * 4 + r) * 168 + jt * 16 + ln15] = f2bf(s[jt][r]);

    // O = P V  (K padded to 160; P and V pads both zeroed)
    f32x4 o[2] = {{0.f, 0.f, 0.f, 0.f}, {0.f, 0.f, 0.f, 0.f}};
#pragma unroll
    for (int kt = 0; kt < 5; ++kt) {
      const bf16x8 pf = *(const bf16x8*)&ps[ln15 * 168 + kt * 32 + quad * 8];
#pragma unroll
      for (int nt = 0; nt < 2; ++nt) {
        const bf16x8 vf = *(const bf16x8*)&Vs[(nt * 16 + ln15) * 160 + kt * 32 + quad * 8];
        o[nt] = __builtin_amdgcn_mfma_f32_16x16x32_bf16(pf, vf, o[nt], 0, 0, 0);
      }
    }

    // store O (bf16) into [m=bw*144+i][c=h*32+d]
#pragma unroll
    for (int nt = 0; nt < 2; ++nt)
#pragma unroll
      for (int r = 0; r < 4; ++r)
        ao[(size_t)(bw * NTOK + ib + r) * DIM + h * HD + nt * 16 + ln15] =
            f2bf(o[nt][r] * rinv[r]);
  }
}

// ---------------------------------------------------------------------------
// Kernel 3: proj GEMM, all-bf16 staging (unchanged from R5).
// ---------------------------------------------------------------------------
__global__ __launch_bounds__(256) void proj_gemm_k(
    const unsigned short* __restrict__ AO, const unsigned short* __restrict__ W,
    const float* __restrict__ Bv, float* __restrict__ out) {
  __shared__ unsigned short As[256 * 72];
  __shared__ unsigned short Bs[64 * 72];
  const int t    = threadIdx.x;
  const int n0   = blockIdx.x * 64;
  const int m0   = blockIdx.y * 256;
  const int w    = t >> 6;
  const int lane = t & 63;
  const int ln15 = lane & 15;
  const int quad = lane >> 4;
  const int srow = t >> 3;
  const int schk = (t & 7) * 8;

  f32x4 acc[4][4];
#pragma unroll
  for (int i = 0; i < 4; ++i)
#pragma unroll
    for (int j = 0; j < 4; ++j) acc[i][j] = (f32x4){0.f, 0.f, 0.f, 0.f};

  for (int k0 = 0; k0 < 192; k0 += 64) {
    u16x8 ar[8], br[2];
#pragma unroll
    for (int rr = 0; rr < 8; ++rr)
      ar[rr] = *(const u16x8*)&AO[(size_t)(m0 + rr * 32 + srow) * 192 + k0 + schk];
#pragma unroll
    for (int rr = 0; rr < 2; ++rr)
      br[rr] = *(const u16x8*)&W[(size_t)(n0 + rr * 32 + srow) * 192 + k0 + schk];
    __syncthreads();
#pragma unroll
    for (int rr = 0; rr < 8; ++rr)
      *(u16x8*)&As[(rr * 32 + srow) * 72 + schk] = ar[rr];
#pragma unroll
    for (int rr = 0; rr < 2; ++rr)
      *(u16x8*)&Bs[(rr * 32 + srow) * 72 + schk] = br[rr];
    __syncthreads();

#pragma unroll
    for (int half = 0; half < 2; ++half) {
      bf16x8 af[4], bf[4];
#pragma unroll
      for (int mt = 0; mt < 4; ++mt)
        af[mt] = *(bf16x8*)&As[(w * 64 + mt * 16 + ln15) * 72 + half * 32 + quad * 8];
#pragma unroll
      for (int nt = 0; nt < 4; ++nt)
        bf[nt] = *(bf16x8*)&Bs[(nt * 16 + ln15) * 72 + half * 32 + quad * 8];
#pragma unroll
      for (int mt = 0; mt < 4; ++mt)
#pragma unroll
        for (int nt = 0; nt < 4; ++nt)
          acc[mt][nt] = __builtin_amdgcn_mfma_f32_16x16x32_bf16(
              af[mt], bf[nt], acc[mt][nt], 0, 0, 0);
    }
    __syncthreads();
  }

#pragma unroll
  for (int nt = 0; nt < 4; ++nt) {
    const int colg = n0 + nt * 16 + ln15;
    const float bias = Bv[colg];
#pragma unroll
    for (int mt = 0; mt < 4; ++mt) {
#pragma unroll
      for (int r = 0; r < 4; ++r) {
        const int m = m0 + w * 64 + mt * 16 + quad * 4 + r;
        out[(size_t)m * 192 + colg] = acc[mt][nt][r] + bias;
      }
    }
  }
}

// ---------------------------------------------------------------------------
extern "C" void kernel_launch(void* const* d_in, const int* in_sizes, int n_in,
                              void* d_out, int out_size, void* d_ws, size_t ws_size,
                              hipStream_t stream) {
  const float* x      = (const float*)d_in[0];
  const float* mask   = (const float*)d_in[1];
  const float* qkv_w  = (const float*)d_in[2];
  const float* qkv_b  = (const float*)d_in[3];
  const float* proj_w = (const float*)d_in[4];
  const float* proj_b = (const float*)d_in[5];
  const float* btab   = (const float*)d_in[6];
  const int*   pos    = (const int*)d_in[7];
  float* out = (float*)d_out;

  unsigned short* ws = (unsigned short*)d_ws;
  const size_t sz = (size_t)MROWS * DIM;   // 13,271,040 elements
  unsigned short* qbuf  = ws;
  unsigned short* kbuf  = ws + sz;
  unsigned short* vbuf  = ws + 2 * sz;
  unsigned short* aobuf = ws + 3 * sz + 256;
  unsigned short* biasb = ws + 4 * sz + 1024;           // 192*20736 bf16 = 8 MB
  unsigned short* xbf   = biasb + (size_t)192 * NN;
  unsigned short* qwbf  = xbf + sz;
  unsigned short* pwbf  = qwbf + (size_t)K3 * DIM;

  conv_bf_k<<<NX8 / 256 + NQ8 / 256 + NP8 / 256, 256, 0, stream>>>(
      x, qkv_w, proj_w, xbf, qwbf, pwbf);
  bias_pre_k<<<dim3(NW * NH, 9), 256, 0, stream>>>(btab, pos, biasb);
  qkv_gemm_k<<<dim3(K3 / 64, MROWS / 256), 256, 0, stream>>>(
      xbf, qwbf, qkv_b, qbuf, kbuf, vbuf);
  attn_k<<<NH * 480, 192, 0, stream>>>(
      qbuf, kbuf, vbuf, mask, biasb, aobuf);
  proj_gemm_k<<<dim3(DIM / 64, MROWS / 256), 256, 0, stream>>>(
      aobuf, pwbf, proj_b, out);
}